// Round 5
// baseline (151.799 us; speedup 1.0000x reference)
//
#include <hip/hip_runtime.h>

#define NN   25
#define DD   128
#define HH   64
#define KK   4
#define RADF 2.5f

#define XBP  136   // ushort stride, [25][128] bf16 x rows (272B, 16B-aligned)
#define AGP  136   // ushort stride, agg rows
#define HSP  72    // ushort stride, hsum/g1 rows (144B, 16B-aligned)
#define YSP  132   // f32 stride, y staging

// ws layout (ushort units)
#define O_W1T 0        // [64][288]  ew1^T + bias row(k=259) + zero pad
#define O_W2T 18432    // [128][64]  ew2^T
#define O_N1T 26624    // [64][256]  nw1^T
#define O_N2T 43008    // [128][64]  nw2^T

typedef __attribute__((ext_vector_type(8))) short  short8;
typedef __attribute__((ext_vector_type(4))) float  f32x4;

__device__ __forceinline__ ushort f2bf(float x) {
    uint u = __float_as_uint(x);
    u += 0x7fffu + ((u >> 16) & 1u);          // RNE
    return (ushort)(u >> 16);
}
__device__ __forceinline__ float bf2f(ushort u) {
    return __uint_as_float((uint)u << 16);
}
__device__ __forceinline__ uint pack2(float a, float b) {
    return (uint)f2bf(a) | ((uint)f2bf(b) << 16);
}
__device__ __forceinline__ short8 ldw(const ushort* p) {
    return *reinterpret_cast<const short8*>(p);
}
#define MFMA16(a, b, c) __builtin_amdgcn_mfma_f32_16x16x32_bf16((a), (b), (c), 0, 0, 0)

__global__ void prep_kernel(const float* __restrict__ ew1, const float* __restrict__ eb1,
                            const float* __restrict__ ew2, const float* __restrict__ nw1,
                            const float* __restrict__ nw2, ushort* __restrict__ w) {
    int tid = blockIdx.x * blockDim.x + threadIdx.x;
    int stride = gridDim.x * blockDim.x;
    for (int e = tid; e < 64 * 288; e += stride) {
        int c = e / 288, k = e % 288;
        float v = (k < 259) ? ew1[(size_t)k * 64 + c] : (k == 259 ? eb1[c] : 0.f);
        w[O_W1T + e] = f2bf(v);
    }
    for (int e = tid; e < 128 * 64; e += stride) {
        int d = e >> 6, k = e & 63;
        w[O_W2T + e] = f2bf(ew2[(size_t)k * 128 + d]);
    }
    for (int e = tid; e < 64 * 256; e += stride) {
        int c = e >> 8, k = e & 255;
        w[O_N1T + e] = f2bf(nw1[(size_t)k * 64 + c]);
    }
    for (int e = tid; e < 128 * 64; e += stride) {
        int d = e >> 6, k = e & 63;
        w[O_N2T + e] = f2bf(nw2[(size_t)k * 128 + d]);
    }
}

__global__ __launch_bounds__(256, 6) void ig5_kernel(
    const float* __restrict__ emb,      // [BT,25,128]
    const float* __restrict__ bboxes,   // [BT,25,4]
    const int*   __restrict__ pmask,    // [BT,25]
    const float* __restrict__ eb2,
    const float* __restrict__ nb1,
    const float* __restrict__ nb2,
    const float* __restrict__ lng,
    const float* __restrict__ lnb,
    const ushort* __restrict__ W,       // prepped bf16 transposed weights
    float* __restrict__ out)
{
    const int bt  = blockIdx.x;
    const int t   = threadIdx.x;
    const int wv  = t >> 6;
    const int ln  = t & 63;
    const int g   = ln >> 4;     // k-chunk / C-row group (0..3)
    const int r16 = ln & 15;

    __shared__ ushort s_xb[NN * XBP];                     // 6800 B, bf16 x
    __shared__ __align__(16) char s_big[13312];           // hs|ag, later y_st
    __shared__ float  s_red[NN][2][2];
    __shared__ ushort s_epk[NN][KK][4];                   // e0,e1,e2,1.0 (bf16)
    __shared__ float  s_val[NN][KK];
    __shared__ int    s_idx[NN][KK];
    __shared__ float  s_cx[NN], s_cy[NN], s_hv[NN];
    __shared__ int    s_m[NN];
    __shared__ float  s_cnt[NN], s_invd[NN], s_has[NN];

    ushort* s_hs = reinterpret_cast<ushort*>(s_big);            // [25][72]
    ushort* s_g1 = s_hs;                                        // alias, after E2
    ushort* s_ag = reinterpret_cast<ushort*>(s_big + 3616);     // [25][136]
    float*  y_st = reinterpret_cast<float*>(s_big);             // [25][132], after B5

    // ---------------- P0: stage x (bf16) + boxes/mask ----------------
    {
        const float4* src4 = reinterpret_cast<const float4*>(emb + (size_t)bt * (NN * DD));
        for (int u = t; u < NN * 16; u += 256) {
            int row = u >> 4, q = u & 15;
            float4 f0 = src4[row * 32 + q * 2];
            float4 f1 = src4[row * 32 + q * 2 + 1];
            uint4 p;
            p.x = pack2(f0.x, f0.y); p.y = pack2(f0.z, f0.w);
            p.z = pack2(f1.x, f1.y); p.w = pack2(f1.z, f1.w);
            *reinterpret_cast<uint4*>(&s_xb[row * XBP + q * 8]) = p;
        }
        if (t < NN) {
            const float* bb = bboxes + ((size_t)bt * NN + t) * 4;
            s_cx[t] = bb[0];
            s_cy[t] = bb[1];
            s_hv[t] = fmaxf(bb[3], 1e-6f);
            s_m[t]  = pmask[(size_t)bt * NN + t];
        }
    }
    // P1 runs on lanes t<25 (all in wave 0): wave-synchronous with its P0 writes.
    if (t < NN) {
        const int n     = t;
        const float inv = 1.0f / s_hv[n];
        const float cxn = s_cx[n], cyn = s_cy[n];
        const int   mn  = s_m[n];
        float best[KK] = {1e30f, 1e30f, 1e30f, 1e30f};
        int   bidx[KK] = {0, 0, 0, 0};
        for (int j = 0; j < NN; ++j) {
            float dx = cxn - s_cx[j], dy = cyn - s_cy[j];
            float dn = sqrtf(fmaf(dx, dx, fmaf(dy, dy, 1e-6f))) * inv;
            bool  pv = (mn != 0) && (s_m[j] != 0) && (j != n);
            float cv = pv ? dn : 1e6f;
            int   ci = j;
#pragma unroll
            for (int kk = 0; kk < KK; ++kk) {         // stable insertion, lowest idx on tie
                if (cv < best[kk]) {
                    float tv = best[kk]; best[kk] = cv; cv = tv;
                    int   ti = bidx[kk]; bidx[kk] = ci; ci = ti;
                }
            }
        }
        float cnt = 0.f;
#pragma unroll
        for (int k = 0; k < KK; ++k) {
            int bj = bidx[k];
            s_idx[n][k] = bj;
            float val = (best[k] < RADF) ? 1.f : 0.f;
            cnt += val;
            s_val[n][k] = val;
            float dx = cxn - s_cx[bj], dy = cyn - s_cy[bj];
            float e0 = dx * inv, e1 = dy * inv;
            float e2 = sqrtf(fmaf(dx, dx, fmaf(dy, dy, 1e-6f))) * inv;
            s_epk[n][k][0] = f2bf(e0);
            s_epk[n][k][1] = f2bf(e1);
            s_epk[n][k][2] = f2bf(e2);
            s_epk[n][k][3] = 0x3F80;   // 1.0 (bias channel)
        }
        s_cnt[n]  = cnt;
        s_invd[n] = 1.0f / fmaxf(cnt, 1.0f);
        s_has[n]  = (cnt > 0.f) ? 1.f : 0.f;
    }
    __syncthreads();   // B1

    // ---------------- E1: unified edge GEMM [112 x 288] @ [288 x 64] -------------
    // tile T rows = edges 16T..16T+15; lane(g,r16): A-row r16, C-rows 4g+q (node 4T+g)
    for (int T = wv; T < 7; T += 4) {
        int rg  = 16 * T + r16;
        int n_a = rg >> 2; if (n_a > 24) n_a = 24;
        int ke  = rg & 3;
        int jn  = s_idx[n_a][ke];
        const ushort* Ai = s_xb + n_a * XBP + g * 8;
        const ushort* Aj = s_xb + jn  * XBP + g * 8;
        short8 ea;
        {
            union { short8 s; uint u[4]; } uu;
            uu.u[0] = uu.u[1] = uu.u[2] = uu.u[3] = 0;
            if (g == 0) {
                uint2 ep = *reinterpret_cast<const uint2*>(&s_epk[n_a][ke][0]);
                uu.u[0] = ep.x; uu.u[1] = ep.y;
            }
            ea = uu.s;
        }
        f32x4 c[4] = {{0,0,0,0},{0,0,0,0},{0,0,0,0},{0,0,0,0}};
#pragma unroll
        for (int kt = 0; kt < 4; ++kt) {
            short8 a = ldw(Ai + kt * 32);
#pragma unroll
            for (int nt = 0; nt < 4; ++nt)
                c[nt] = MFMA16(a, ldw(W + O_W1T + (size_t)(16 * nt + r16) * 288 + kt * 32 + g * 8), c[nt]);
        }
#pragma unroll
        for (int kt = 4; kt < 8; ++kt) {
            short8 a = ldw(Aj + (kt - 4) * 32);
#pragma unroll
            for (int nt = 0; nt < 4; ++nt)
                c[nt] = MFMA16(a, ldw(W + O_W1T + (size_t)(16 * nt + r16) * 288 + kt * 32 + g * 8), c[nt]);
        }
#pragma unroll
        for (int nt = 0; nt < 4; ++nt)
            c[nt] = MFMA16(ea, ldw(W + O_W1T + (size_t)(16 * nt + r16) * 288 + 256 + g * 8), c[nt]);

        const int n = 4 * T + g;
        if (n < 25) {
            float v0 = s_val[n][0], v1 = s_val[n][1], v2 = s_val[n][2], v3 = s_val[n][3];
#pragma unroll
            for (int nt = 0; nt < 4; ++nt) {
                float hs = fmaf(v0, fmaxf(c[nt][0], 0.f),
                           fmaf(v1, fmaxf(c[nt][1], 0.f),
                           fmaf(v2, fmaxf(c[nt][2], 0.f),
                                v3 * fmaxf(c[nt][3], 0.f))));
                s_hs[n * HSP + 16 * nt + r16] = f2bf(hs);
            }
        }
    }
    __syncthreads();   // B2

    // ---------------- E2: agg = (hsum @ W2 + cnt*b2) * invd -> bf16 ---------------
    {
        const int mt  = wv & 1;
        const int nth = (wv >> 1) * 4;
        int n_a = 16 * mt + r16; if (n_a > 24) n_a = 24;
        const ushort* A = s_hs + n_a * HSP + g * 8;
        f32x4 c[4] = {{0,0,0,0},{0,0,0,0},{0,0,0,0},{0,0,0,0}};
#pragma unroll
        for (int kt = 0; kt < 2; ++kt) {
            short8 a = ldw(A + kt * 32);
#pragma unroll
            for (int nt = 0; nt < 4; ++nt)
                c[nt] = MFMA16(a, ldw(W + O_W2T + (size_t)((nth + nt) * 16 + r16) * 64 + kt * 32 + g * 8), c[nt]);
        }
#pragma unroll
        for (int nt = 0; nt < 4; ++nt) {
            int col = (nth + nt) * 16 + r16;
            float b2c = eb2[col];
#pragma unroll
            for (int q = 0; q < 4; ++q) {
                int nr = 16 * mt + 4 * g + q;
                if (nr < 25)
                    s_ag[nr * AGP + col] = f2bf(s_invd[nr] * fmaf(s_cnt[nr], b2c, c[nt][q]));
            }
        }
    }
    __syncthreads();   // B3

    // ---------------- N1: g1 = relu([x|agg] @ nW1 + nb1) -> bf16 (aliases hs) -----
    {
        const int mt  = wv & 1;
        const int ntb = (wv >> 1) * 2;
        int n_a = 16 * mt + r16; if (n_a > 24) n_a = 24;
        const ushort* Ax = s_xb + n_a * XBP + g * 8;
        const ushort* Aa = s_ag + n_a * AGP + g * 8;
        f32x4 c[2] = {{0,0,0,0},{0,0,0,0}};
#pragma unroll
        for (int kt = 0; kt < 4; ++kt) {
            short8 a = ldw(Ax + kt * 32);
#pragma unroll
            for (int nt = 0; nt < 2; ++nt)
                c[nt] = MFMA16(a, ldw(W + O_N1T + (size_t)((ntb + nt) * 16 + r16) * 256 + kt * 32 + g * 8), c[nt]);
        }
#pragma unroll
        for (int kt = 0; kt < 4; ++kt) {
            short8 a = ldw(Aa + kt * 32);
#pragma unroll
            for (int nt = 0; nt < 2; ++nt)
                c[nt] = MFMA16(a, ldw(W + O_N1T + (size_t)((ntb + nt) * 16 + r16) * 256 + 128 + kt * 32 + g * 8), c[nt]);
        }
#pragma unroll
        for (int nt = 0; nt < 2; ++nt) {
            int col = (ntb + nt) * 16 + r16;
            float b1c = nb1[col];
#pragma unroll
            for (int q = 0; q < 4; ++q) {
                int nr = 16 * mt + 4 * g + q;
                if (nr < 25)
                    s_g1[nr * HSP + col] = f2bf(fmaxf(c[nt][q] + b1c, 0.f));
            }
        }
    }
    __syncthreads();   // B4

    // ---------------- N2: delta GEMM + residual(bf16 x) + LN + staged store -------
    {
        const int mt  = wv & 1;
        const int nth = (wv >> 1) * 4;
        int n_a = 16 * mt + r16; if (n_a > 24) n_a = 24;
        const ushort* A = s_g1 + n_a * HSP + g * 8;
        f32x4 c[4] = {{0,0,0,0},{0,0,0,0},{0,0,0,0},{0,0,0,0}};
#pragma unroll
        for (int kt = 0; kt < 2; ++kt) {
            short8 a = ldw(A + kt * 32);
#pragma unroll
            for (int nt = 0; nt < 4; ++nt)
                c[nt] = MFMA16(a, ldw(W + O_N2T + (size_t)((nth + nt) * 16 + r16) * 64 + kt * 32 + g * 8), c[nt]);
        }
        float y[4][4];
#pragma unroll
        for (int q = 0; q < 4; ++q) {
            int nr = 16 * mt + 4 * g + q;
            int nc = nr < 25 ? nr : 24;
            float hasv = s_has[nc];
#pragma unroll
            for (int nt = 0; nt < 4; ++nt) {
                int col = (nth + nt) * 16 + r16;
                float xv = bf2f(s_xb[nc * XBP + col]);
                y[q][nt] = fmaf(hasv, c[nt][q] + nb2[col], xv);
            }
        }
        float sm[4], s2[4];
#pragma unroll
        for (int q = 0; q < 4; ++q) {
            float a = (y[q][0] + y[q][1]) + (y[q][2] + y[q][3]);
            float b = fmaf(y[q][0], y[q][0], fmaf(y[q][1], y[q][1],
                      fmaf(y[q][2], y[q][2], y[q][3] * y[q][3])));
#pragma unroll
            for (int o = 1; o < 16; o <<= 1) {
                a += __shfl_xor(a, o);
                b += __shfl_xor(b, o);
            }
            sm[q] = a; s2[q] = b;
        }
        if (r16 == 0) {
#pragma unroll
            for (int q = 0; q < 4; ++q) {
                int nr = 16 * mt + 4 * g + q;
                if (nr < 25) {
                    s_red[nr][wv >> 1][0] = sm[q];
                    s_red[nr][wv >> 1][1] = s2[q];
                }
            }
        }
        __syncthreads();   // B5  (g1 dead after this; y_st aliases it)
#pragma unroll
        for (int q = 0; q < 4; ++q) {
            int nr = 16 * mt + 4 * g + q;
            if (nr < 25) {
                float S   = s_red[nr][0][0] + s_red[nr][1][0];
                float S2  = s_red[nr][0][1] + s_red[nr][1][1];
                float mu  = S * (1.0f / 128.0f);
                float var = S2 * (1.0f / 128.0f) - mu * mu;
                float rs  = rsqrtf(var + 1e-5f);
                float mk  = s_m[nr] ? 1.f : 0.f;
#pragma unroll
                for (int nt = 0; nt < 4; ++nt) {
                    int col = (nth + nt) * 16 + r16;
                    y_st[nr * YSP + col] = fmaf((y[q][nt] - mu) * rs, lng[col], lnb[col]) * mk;
                }
            }
        }
    }
    __syncthreads();   // B6

    // ---------------- P7: coalesced copy-out (full-line stores) -------------------
    {
        float* op = out + (size_t)bt * (NN * DD);
        for (int u = t; u < NN * 32; u += 256) {
            int row = u >> 5, q = u & 31;
            *reinterpret_cast<float4*>(op + row * DD + q * 4) =
                *reinterpret_cast<const float4*>(y_st + row * YSP + q * 4);
        }
    }
}

extern "C" void kernel_launch(void* const* d_in, const int* in_sizes, int n_in,
                              void* d_out, int out_size, void* d_ws, size_t ws_size,
                              hipStream_t stream) {
    const float* emb    = (const float*)d_in[0];
    const float* bboxes = (const float*)d_in[1];
    const int*   pmask  = (const int*)  d_in[2];
    const float* ew1    = (const float*)d_in[3];
    const float* eb1    = (const float*)d_in[4];
    const float* ew2    = (const float*)d_in[5];
    const float* eb2    = (const float*)d_in[6];
    const float* nw1    = (const float*)d_in[7];
    const float* nb1    = (const float*)d_in[8];
    const float* nw2    = (const float*)d_in[9];
    const float* nb2    = (const float*)d_in[10];
    const float* lng    = (const float*)d_in[11];
    const float* lnb    = (const float*)d_in[12];
    float* out = (float*)d_out;
    ushort* W  = (ushort*)d_ws;

    prep_kernel<<<64, 256, 0, stream>>>(ew1, eb1, ew2, nw1, nw2, W);

    const int BT = in_sizes[2] / NN;   // 2048 frames
    ig5_kernel<<<BT, 256, 0, stream>>>(
        emb, bboxes, pmask, eb2, nb1, nb2, lng, lnb, W, out);
}

// Round 6
// 114.755 us; speedup vs baseline: 1.3228x; 1.3228x over previous
//
#include <hip/hip_runtime.h>

#define NN   25
#define DD   128
#define HH   64
#define KK   4
#define RADF 2.5f

#define XBP  136   // ushort stride, [25][128] bf16 x rows (272B, 16B-aligned)
#define AGP  136   // ushort stride, agg rows
#define HSP  72    // ushort stride, hsum/g1 rows (144B, 16B-aligned)
#define YSP  132   // f32 stride, y staging

// ws layout (ushort units)
#define O_W1T 0        // [64][288]  ew1^T + bias row(k=259) + zero pad
#define O_W2T 18432    // [128][64]  ew2^T
#define O_N1T 26624    // [64][256]  nw1^T
#define O_N2T 43008    // [128][64]  nw2^T

typedef __attribute__((ext_vector_type(8))) short  short8;
typedef __attribute__((ext_vector_type(4))) float  f32x4;

__device__ __forceinline__ ushort f2bf(float x) {
    uint u = __float_as_uint(x);
    u += 0x7fffu + ((u >> 16) & 1u);          // RNE
    return (ushort)(u >> 16);
}
__device__ __forceinline__ float bf2f(ushort u) {
    return __uint_as_float((uint)u << 16);
}
__device__ __forceinline__ uint pack2(float a, float b) {
    return (uint)f2bf(a) | ((uint)f2bf(b) << 16);
}
__device__ __forceinline__ short8 ldw(const ushort* p) {
    return *reinterpret_cast<const short8*>(p);
}
#define MFMA16(a, b, c) __builtin_amdgcn_mfma_f32_16x16x32_bf16((a), (b), (c), 0, 0, 0)

__global__ void prep_kernel(const float* __restrict__ ew1, const float* __restrict__ eb1,
                            const float* __restrict__ ew2, const float* __restrict__ nw1,
                            const float* __restrict__ nw2, ushort* __restrict__ w) {
    int tid = blockIdx.x * blockDim.x + threadIdx.x;
    int stride = gridDim.x * blockDim.x;
    for (int e = tid; e < 64 * 288; e += stride) {
        int c = e / 288, k = e % 288;
        float v = (k < 259) ? ew1[(size_t)k * 64 + c] : (k == 259 ? eb1[c] : 0.f);
        w[O_W1T + e] = f2bf(v);
    }
    for (int e = tid; e < 128 * 64; e += stride) {
        int d = e >> 6, k = e & 63;
        w[O_W2T + e] = f2bf(ew2[(size_t)k * 128 + d]);
    }
    for (int e = tid; e < 64 * 256; e += stride) {
        int c = e >> 8, k = e & 255;
        w[O_N1T + e] = f2bf(nw1[(size_t)k * 64 + c]);
    }
    for (int e = tid; e < 128 * 64; e += stride) {
        int d = e >> 6, k = e & 63;
        w[O_N2T + e] = f2bf(nw2[(size_t)k * 128 + d]);
    }
}

__global__ __launch_bounds__(256, 4) void ig6_kernel(
    const float* __restrict__ emb,      // [BT,25,128]
    const float* __restrict__ bboxes,   // [BT,25,4]
    const int*   __restrict__ pmask,    // [BT,25]
    const float* __restrict__ eb2,
    const float* __restrict__ nb1,
    const float* __restrict__ nb2,
    const float* __restrict__ lng,
    const float* __restrict__ lnb,
    const ushort* __restrict__ W,       // prepped bf16 transposed weights
    float* __restrict__ out)
{
    const int bt  = blockIdx.x;
    const int t   = threadIdx.x;
    const int wv  = t >> 6;
    const int ln  = t & 63;
    const int g   = ln >> 4;     // k-chunk / C-row group (0..3)
    const int r16 = ln & 15;

    __shared__ ushort s_xb[NN * XBP];               // 6800 B, bf16 x
    __shared__ ushort s_hs[NN * HSP];               // 3600 B, hsum then g1
    __shared__ ushort s_ag[NN * AGP];               // 6800 B, agg
    __shared__ float  y_st[NN * YSP];               // 13200 B, raw y staging
    __shared__ float  s_red[NN][2][2];
    __shared__ __align__(16) ushort s_epk[NN][KK][8];  // e0,e1,e2,1.0,0,0,0,0
    __shared__ float  s_val[NN][KK];
    __shared__ int    s_idx[NN][KK];
    __shared__ float  s_cx[NN], s_cy[NN], s_hv[NN];
    __shared__ int    s_m[NN];
    __shared__ float  s_cnt[NN], s_invd[NN], s_has[NN];

    ushort* s_g1 = s_hs;   // alias: hs dead after E2 (B3), g1 written after B3

    // ---------------- P0: stage x (bf16) + boxes/mask ----------------
    {
        const float4* src4 = reinterpret_cast<const float4*>(emb + (size_t)bt * (NN * DD));
        for (int u = t; u < NN * 16; u += 256) {
            int row = u >> 4, q = u & 15;
            float4 f0 = src4[row * 32 + q * 2];
            float4 f1 = src4[row * 32 + q * 2 + 1];
            uint4 p;
            p.x = pack2(f0.x, f0.y); p.y = pack2(f0.z, f0.w);
            p.z = pack2(f1.x, f1.y); p.w = pack2(f1.z, f1.w);
            *reinterpret_cast<uint4*>(&s_xb[row * XBP + q * 8]) = p;
        }
        if (t < NN) {
            const float* bb = bboxes + ((size_t)bt * NN + t) * 4;
            s_cx[t] = bb[0];
            s_cy[t] = bb[1];
            s_hv[t] = fmaxf(bb[3], 1e-6f);
            s_m[t]  = pmask[(size_t)bt * NN + t];
        }
    }
    // P1 on lanes t<25 (wave 0): wave-synchronous with its own P0 writes.
    if (t < NN) {
        const int n     = t;
        const float inv = 1.0f / s_hv[n];
        const float cxn = s_cx[n], cyn = s_cy[n];
        const int   mn  = s_m[n];
        float best[KK] = {1e30f, 1e30f, 1e30f, 1e30f};
        int   bidx[KK] = {0, 0, 0, 0};
        for (int j = 0; j < NN; ++j) {
            float dx = cxn - s_cx[j], dy = cyn - s_cy[j];
            float dn = sqrtf(fmaf(dx, dx, fmaf(dy, dy, 1e-6f))) * inv;
            bool  pv = (mn != 0) && (s_m[j] != 0) && (j != n);
            float cv = pv ? dn : 1e6f;
            int   ci = j;
#pragma unroll
            for (int kk = 0; kk < KK; ++kk) {       // stable insertion, lowest idx on tie
                if (cv < best[kk]) {
                    float tv = best[kk]; best[kk] = cv; cv = tv;
                    int   ti = bidx[kk]; bidx[kk] = ci; ci = ti;
                }
            }
        }
        float cnt = 0.f;
#pragma unroll
        for (int k = 0; k < KK; ++k) {
            int bj = bidx[k];
            s_idx[n][k] = bj;
            float val = (best[k] < RADF) ? 1.f : 0.f;
            cnt += val;
            s_val[n][k] = val;
            float dx = cxn - s_cx[bj], dy = cyn - s_cy[bj];
            float e0 = dx * inv, e1 = dy * inv;
            float e2 = sqrtf(fmaf(dx, dx, fmaf(dy, dy, 1e-6f))) * inv;
            s_epk[n][k][0] = f2bf(e0);
            s_epk[n][k][1] = f2bf(e1);
            s_epk[n][k][2] = f2bf(e2);
            s_epk[n][k][3] = 0x3F80;   // 1.0 (bias channel)
            s_epk[n][k][4] = 0; s_epk[n][k][5] = 0;
            s_epk[n][k][6] = 0; s_epk[n][k][7] = 0;
        }
        s_cnt[n]  = cnt;
        s_invd[n] = 1.0f / fmaxf(cnt, 1.0f);
        s_has[n]  = (cnt > 0.f) ? 1.f : 0.f;
    }
    __syncthreads();   // B1

    // ---------------- E1: unified edge GEMM [112 x 288] @ [288 x 64] -------------
    for (int T = wv; T < 7; T += 4) {
        int rg  = 16 * T + r16;
        int n_a = rg >> 2; if (n_a > 24) n_a = 24;
        int ke  = rg & 3;
        int jn  = s_idx[n_a][ke];
        const ushort* Ai = s_xb + n_a * XBP + g * 8;
        const ushort* Aj = s_xb + jn  * XBP + g * 8;
        short8 ea = {0, 0, 0, 0, 0, 0, 0, 0};
        if (g == 0) ea = ldw(&s_epk[n_a][ke][0]);
        f32x4 c[4] = {{0,0,0,0},{0,0,0,0},{0,0,0,0},{0,0,0,0}};
#pragma unroll
        for (int kt = 0; kt < 4; ++kt) {
            short8 a = ldw(Ai + kt * 32);
#pragma unroll
            for (int nt = 0; nt < 4; ++nt)
                c[nt] = MFMA16(a, ldw(W + O_W1T + (size_t)(16 * nt + r16) * 288 + kt * 32 + g * 8), c[nt]);
        }
#pragma unroll
        for (int kt = 4; kt < 8; ++kt) {
            short8 a = ldw(Aj + (kt - 4) * 32);
#pragma unroll
            for (int nt = 0; nt < 4; ++nt)
                c[nt] = MFMA16(a, ldw(W + O_W1T + (size_t)(16 * nt + r16) * 288 + kt * 32 + g * 8), c[nt]);
        }
#pragma unroll
        for (int nt = 0; nt < 4; ++nt)
            c[nt] = MFMA16(ea, ldw(W + O_W1T + (size_t)(16 * nt + r16) * 288 + 256 + g * 8), c[nt]);

        const int n = 4 * T + g;
        if (n < 25) {
            float v0 = s_val[n][0], v1 = s_val[n][1], v2 = s_val[n][2], v3 = s_val[n][3];
#pragma unroll
            for (int nt = 0; nt < 4; ++nt) {
                float hs = fmaf(v0, fmaxf(c[nt][0], 0.f),
                           fmaf(v1, fmaxf(c[nt][1], 0.f),
                           fmaf(v2, fmaxf(c[nt][2], 0.f),
                                v3 * fmaxf(c[nt][3], 0.f))));
                s_hs[n * HSP + 16 * nt + r16] = f2bf(hs);
            }
        }
    }
    __syncthreads();   // B2

    // ---------------- E2: agg = (hsum @ W2 + cnt*b2) * invd -> bf16 ---------------
    {
        const int mt  = wv & 1;
        const int nth = (wv >> 1) * 4;
        int n_a = 16 * mt + r16; if (n_a > 24) n_a = 24;
        const ushort* A = s_hs + n_a * HSP + g * 8;
        f32x4 c[4] = {{0,0,0,0},{0,0,0,0},{0,0,0,0},{0,0,0,0}};
#pragma unroll
        for (int kt = 0; kt < 2; ++kt) {
            short8 a = ldw(A + kt * 32);
#pragma unroll
            for (int nt = 0; nt < 4; ++nt)
                c[nt] = MFMA16(a, ldw(W + O_W2T + (size_t)((nth + nt) * 16 + r16) * 64 + kt * 32 + g * 8), c[nt]);
        }
#pragma unroll
        for (int nt = 0; nt < 4; ++nt) {
            int col = (nth + nt) * 16 + r16;
            float b2c = eb2[col];
#pragma unroll
            for (int q = 0; q < 4; ++q) {
                int nr = 16 * mt + 4 * g + q;
                if (nr < 25)
                    s_ag[nr * AGP + col] = f2bf(s_invd[nr] * fmaf(s_cnt[nr], b2c, c[nt][q]));
            }
        }
    }
    __syncthreads();   // B3

    // ---------------- N1: g1 = relu([x|agg] @ nW1 + nb1) -> bf16 (aliases hs) -----
    {
        const int mt  = wv & 1;
        const int ntb = (wv >> 1) * 2;
        int n_a = 16 * mt + r16; if (n_a > 24) n_a = 24;
        const ushort* Ax = s_xb + n_a * XBP + g * 8;
        const ushort* Aa = s_ag + n_a * AGP + g * 8;
        f32x4 c[2] = {{0,0,0,0},{0,0,0,0}};
#pragma unroll
        for (int kt = 0; kt < 4; ++kt) {
            short8 a = ldw(Ax + kt * 32);
#pragma unroll
            for (int nt = 0; nt < 2; ++nt)
                c[nt] = MFMA16(a, ldw(W + O_N1T + (size_t)((ntb + nt) * 16 + r16) * 256 + kt * 32 + g * 8), c[nt]);
        }
#pragma unroll
        for (int kt = 0; kt < 4; ++kt) {
            short8 a = ldw(Aa + kt * 32);
#pragma unroll
            for (int nt = 0; nt < 2; ++nt)
                c[nt] = MFMA16(a, ldw(W + O_N1T + (size_t)((ntb + nt) * 16 + r16) * 256 + 128 + kt * 32 + g * 8), c[nt]);
        }
#pragma unroll
        for (int nt = 0; nt < 2; ++nt) {
            int col = (ntb + nt) * 16 + r16;
            float b1c = nb1[col];
#pragma unroll
            for (int q = 0; q < 4; ++q) {
                int nr = 16 * mt + 4 * g + q;
                if (nr < 25)
                    s_g1[nr * HSP + col] = f2bf(fmaxf(c[nt][q] + b1c, 0.f));
            }
        }
    }
    __syncthreads();   // B4

    // ---------------- N2: delta GEMM + residual; raw y -> y_st; LN partials -------
    {
        const int mt  = wv & 1;
        const int nth = (wv >> 1) * 4;
        int n_a = 16 * mt + r16; if (n_a > 24) n_a = 24;
        const ushort* A = s_g1 + n_a * HSP + g * 8;
        f32x4 c[4] = {{0,0,0,0},{0,0,0,0},{0,0,0,0},{0,0,0,0}};
#pragma unroll
        for (int kt = 0; kt < 2; ++kt) {
            short8 a = ldw(A + kt * 32);
#pragma unroll
            for (int nt = 0; nt < 4; ++nt)
                c[nt] = MFMA16(a, ldw(W + O_N2T + (size_t)((nth + nt) * 16 + r16) * 64 + kt * 32 + g * 8), c[nt]);
        }
#pragma unroll
        for (int q = 0; q < 4; ++q) {
            int nr = 16 * mt + 4 * g + q;
            int nc = nr < 25 ? nr : 24;
            float hasv = s_has[nc];
            float yv[4];
#pragma unroll
            for (int nt = 0; nt < 4; ++nt) {
                int col = (nth + nt) * 16 + r16;
                float xv = bf2f(s_xb[nc * XBP + col]);
                yv[nt] = fmaf(hasv, c[nt][q] + nb2[col], xv);
            }
            float a = (yv[0] + yv[1]) + (yv[2] + yv[3]);
            float b = fmaf(yv[0], yv[0], fmaf(yv[1], yv[1],
                      fmaf(yv[2], yv[2], yv[3] * yv[3])));
#pragma unroll
            for (int o = 1; o < 16; o <<= 1) {
                a += __shfl_xor(a, o);
                b += __shfl_xor(b, o);
            }
            if (nr < 25) {
#pragma unroll
                for (int nt = 0; nt < 4; ++nt)
                    y_st[nr * YSP + (nth + nt) * 16 + r16] = yv[nt];
                if (r16 == 0) {
                    s_red[nr][wv >> 1][0] = a;
                    s_red[nr][wv >> 1][1] = b;
                }
            }
        }
    }
    __syncthreads();   // B5

    // ---------------- P7: LN + mask fused into coalesced copy-out -----------------
    {
        float* op = out + (size_t)bt * (NN * DD);
        for (int u = t; u < NN * 32; u += 256) {
            int row = u >> 5, q4 = u & 31;
            float4 y4 = *reinterpret_cast<const float4*>(y_st + row * YSP + q4 * 4);
            float S   = s_red[row][0][0] + s_red[row][1][0];
            float S2  = s_red[row][0][1] + s_red[row][1][1];
            float mu  = S * (1.0f / 128.0f);
            float var = S2 * (1.0f / 128.0f) - mu * mu;
            float rs  = rsqrtf(var + 1e-5f);
            float mk  = s_m[row] ? 1.f : 0.f;
            float4 g4 = *reinterpret_cast<const float4*>(lng + q4 * 4);
            float4 b4 = *reinterpret_cast<const float4*>(lnb + q4 * 4);
            float4 o4;
            o4.x = fmaf((y4.x - mu) * rs, g4.x, b4.x) * mk;
            o4.y = fmaf((y4.y - mu) * rs, g4.y, b4.y) * mk;
            o4.z = fmaf((y4.z - mu) * rs, g4.z, b4.z) * mk;
            o4.w = fmaf((y4.w - mu) * rs, g4.w, b4.w) * mk;
            *reinterpret_cast<float4*>(op + row * DD + q4 * 4) = o4;
        }
    }
}

extern "C" void kernel_launch(void* const* d_in, const int* in_sizes, int n_in,
                              void* d_out, int out_size, void* d_ws, size_t ws_size,
                              hipStream_t stream) {
    const float* emb    = (const float*)d_in[0];
    const float* bboxes = (const float*)d_in[1];
    const int*   pmask  = (const int*)  d_in[2];
    const float* ew1    = (const float*)d_in[3];
    const float* eb1    = (const float*)d_in[4];
    const float* ew2    = (const float*)d_in[5];
    const float* eb2    = (const float*)d_in[6];
    const float* nw1    = (const float*)d_in[7];
    const float* nb1    = (const float*)d_in[8];
    const float* nw2    = (const float*)d_in[9];
    const float* nb2    = (const float*)d_in[10];
    const float* lng    = (const float*)d_in[11];
    const float* lnb    = (const float*)d_in[12];
    float* out = (float*)d_out;
    ushort* W  = (ushort*)d_ws;

    prep_kernel<<<64, 256, 0, stream>>>(ew1, eb1, ew2, nw1, nw2, W);

    const int BT = in_sizes[2] / NN;   // 2048 frames
    ig6_kernel<<<BT, 256, 0, stream>>>(
        emb, bboxes, pmask, eb2, nb1, nb2, lng, lnb, W, out);
}

// Round 7
// 79.866 us; speedup vs baseline: 1.9007x; 1.4368x over previous
//
#include <hip/hip_runtime.h>

#define NN   25
#define DD   128
#define HH   64
#define KK   4
#define RADF 2.5f

#define XBP  136   // ushort stride, [25][128] bf16 x rows (272B, 16B-aligned)
#define AGP  136   // ushort stride, agg rows (later aliased as bf16 y staging)
#define HSP  72    // ushort stride, hsum/g1 rows (144B, 16B-aligned)
#define HXS  72    // ushort stride, hxi rows (bf16)

// ws layout (ushort units) — identical to R4
#define O_W1T 0        // [64][264]   ew1^T  (k<259)
#define O_W2T 16896    // [128][64]   ew2^T
#define O_N1T 25088    // [64][256]   nw1^T
#define O_N2T 41472    // [128][64]   nw2^T

typedef __attribute__((ext_vector_type(8))) short  short8;
typedef __attribute__((ext_vector_type(4))) float  f32x4;

__device__ __forceinline__ ushort f2bf(float x) {
    uint u = __float_as_uint(x);
    u += 0x7fffu + ((u >> 16) & 1u);          // RNE
    return (ushort)(u >> 16);
}
__device__ __forceinline__ float bf2f(ushort u) {
    return __uint_as_float((uint)u << 16);
}
__device__ __forceinline__ uint pack2(float a, float b) {
    return (uint)f2bf(a) | ((uint)f2bf(b) << 16);
}
__device__ __forceinline__ float2 up2(uint u) {    // unpack 2 bf16 from one dword
    return make_float2(__uint_as_float(u << 16),
                       __uint_as_float(u & 0xffff0000u));
}
__device__ __forceinline__ short8 ldw(const ushort* p) {
    return *reinterpret_cast<const short8*>(p);
}
#define MFMA16(a, b, c) __builtin_amdgcn_mfma_f32_16x16x32_bf16((a), (b), (c), 0, 0, 0)

__global__ void prep_kernel(const float* __restrict__ ew1, const float* __restrict__ ew2,
                            const float* __restrict__ nw1, const float* __restrict__ nw2,
                            ushort* __restrict__ w) {
    int tid = blockIdx.x * blockDim.x + threadIdx.x;
    int stride = gridDim.x * blockDim.x;
    for (int e = tid; e < 259 * 64; e += stride) {
        int k = e >> 6, c = e & 63;
        w[O_W1T + c * 264 + k] = f2bf(ew1[e]);
    }
    for (int e = tid; e < 64 * 128; e += stride) {
        int k = e >> 7, d = e & 127;
        w[O_W2T + d * 64 + k] = f2bf(ew2[e]);
    }
    for (int e = tid; e < 256 * 64; e += stride) {
        int k = e >> 6, c = e & 63;
        w[O_N1T + c * 256 + k] = f2bf(nw1[e]);
    }
    for (int e = tid; e < 64 * 128; e += stride) {
        int k = e >> 7, d = e & 127;
        w[O_N2T + d * 64 + k] = f2bf(nw2[e]);
    }
}

__global__ __launch_bounds__(256, 4) void ig7_kernel(
    const float* __restrict__ emb,      // [BT,25,128]
    const float* __restrict__ bboxes,   // [BT,25,4]
    const int*   __restrict__ pmask,    // [BT,25]
    const float* __restrict__ ew1f,     // [259,64] f32 (e-rows 256..258)
    const float* __restrict__ eb1,
    const float* __restrict__ eb2,
    const float* __restrict__ nb1,
    const float* __restrict__ nb2,
    const float* __restrict__ lng,
    const float* __restrict__ lnb,
    const ushort* __restrict__ W,       // prepped bf16 transposed weights
    float* __restrict__ out)
{
    const int bt  = blockIdx.x;
    const int t   = threadIdx.x;
    const int wv  = t >> 6;
    const int ln  = t & 63;
    const int g   = ln >> 4;     // k-chunk / C-row group (0..3)
    const int r16 = ln & 15;

    __shared__ ushort s_xb[NN * XBP];     // 6800 B  bf16 x (live whole kernel)
    __shared__ ushort s_hxi[NN * HXS];    // 3600 B  bf16 xi-part of edge-L1
    __shared__ ushort s_hs[NN * HSP];     // 3600 B  hsum, then g1 (alias)
    __shared__ ushort s_ag[NN * AGP];     // 6800 B  agg, then bf16 y (alias)
    __shared__ float  s_red[NN][2][2];    // 400 B
    __shared__ float  s_e[NN][KK][3];     // 1200 B
    __shared__ float  s_val[NN][KK];
    __shared__ int    s_idx[NN][KK];
    __shared__ float  s_cx[NN], s_cy[NN], s_hv[NN];
    __shared__ int    s_m[NN];
    __shared__ float  s_cnt[NN], s_invd[NN], s_has[NN];
    // total ~24 KB -> 6 blocks/CU (LDS-limited), VGPR 64 -> not binding

    ushort* s_g1  = s_hs;   // g1 overlays hsum after E2 (B3)
    ushort* y_stb = s_ag;   // bf16 y overlays agg after N1 (B4)

    // ---------------- P0: stage x (bf16) + boxes/mask ----------------
    {
        const float4* src4 = reinterpret_cast<const float4*>(emb + (size_t)bt * (NN * DD));
        for (int u = t; u < NN * 16; u += 256) {
            int row = u >> 4, q = u & 15;
            float4 f0 = src4[row * 32 + q * 2];
            float4 f1 = src4[row * 32 + q * 2 + 1];
            uint4 p;
            p.x = pack2(f0.x, f0.y); p.y = pack2(f0.z, f0.w);
            p.z = pack2(f1.x, f1.y); p.w = pack2(f1.z, f1.w);
            *reinterpret_cast<uint4*>(&s_xb[row * XBP + q * 8]) = p;
        }
        if (t < NN) {
            const float* bb = bboxes + ((size_t)bt * NN + t) * 4;
            s_cx[t] = bb[0];
            s_cy[t] = bb[1];
            s_hv[t] = fmaxf(bb[3], 1e-6f);
            s_m[t]  = pmask[(size_t)bt * NN + t];
        }
    }
    // P1 on lanes t<25 (all wave 0): wave-synchronous with its own P0 writes.
    if (t < NN) {
        const int n     = t;
        const float inv = 1.0f / s_hv[n];
        const float cxn = s_cx[n], cyn = s_cy[n];
        const int   mn  = s_m[n];
        float best[KK] = {1e30f, 1e30f, 1e30f, 1e30f};
        int   bidx[KK] = {0, 0, 0, 0};
        for (int j = 0; j < NN; ++j) {
            float dx = cxn - s_cx[j], dy = cyn - s_cy[j];
            float dn = sqrtf(fmaf(dx, dx, fmaf(dy, dy, 1e-6f))) * inv;
            bool  pv = (mn != 0) && (s_m[j] != 0) && (j != n);
            float cv = pv ? dn : 1e6f;
            int   ci = j;
#pragma unroll
            for (int kk = 0; kk < KK; ++kk) {       // stable insertion, lowest idx on tie
                if (cv < best[kk]) {
                    float tv = best[kk]; best[kk] = cv; cv = tv;
                    int   ti = bidx[kk]; bidx[kk] = ci; ci = ti;
                }
            }
        }
        float cnt = 0.f;
#pragma unroll
        for (int k = 0; k < KK; ++k) {
            int bj = bidx[k];
            s_idx[n][k] = bj;
            float val = (best[k] < RADF) ? 1.f : 0.f;
            cnt += val;
            s_val[n][k] = val;
            float dx = cxn - s_cx[bj], dy = cyn - s_cy[bj];
            s_e[n][k][0] = dx * inv;
            s_e[n][k][1] = dy * inv;
            s_e[n][k][2] = sqrtf(fmaf(dx, dx, fmaf(dy, dy, 1e-6f))) * inv;
        }
        s_cnt[n]  = cnt;
        s_invd[n] = 1.0f / fmaxf(cnt, 1.0f);
        s_has[n]  = (cnt > 0.f) ? 1.f : 0.f;
    }
    __syncthreads();   // B1

    // ---------------- E1a: hxi[25][64] = x @ W1[0:128]  (waves 0,1) ---------------
    if (wv < 2) {
        const int mt = wv;
        int n = 16 * mt + r16; if (n > 24) n = 24;
        const ushort* A = s_xb + n * XBP + g * 8;
        f32x4 c[4] = {{0,0,0,0},{0,0,0,0},{0,0,0,0},{0,0,0,0}};
#pragma unroll
        for (int kt = 0; kt < 4; ++kt) {
            short8 a = ldw(A + kt * 32);
#pragma unroll
            for (int nt = 0; nt < 4; ++nt)
                c[nt] = MFMA16(a, ldw(W + O_W1T + (size_t)(16 * nt + r16) * 264 + kt * 32 + g * 8), c[nt]);
        }
#pragma unroll
        for (int q = 0; q < 4; ++q) {
            int nr = 16 * mt + 4 * g + q;
            if (nr < 25) {
#pragma unroll
                for (int nt = 0; nt < 4; ++nt)
                    s_hxi[nr * HXS + 16 * nt + r16] = f2bf(c[nt][q]);
            }
        }
    }
    __syncthreads();   // B2

    // ---------------- E1b: xj GEMM + fused relu/val-k-sum -> hsum bf16 ------------
    for (int T = wv; T < 7; T += 4) {
        int r = 16 * T + r16; if (r > 99) r = 99;
        const int jn = s_idx[r >> 2][r & 3];
        const ushort* A = s_xb + jn * XBP + g * 8;
        f32x4 c[4] = {{0,0,0,0},{0,0,0,0},{0,0,0,0},{0,0,0,0}};
#pragma unroll
        for (int kt = 0; kt < 4; ++kt) {
            short8 a = ldw(A + kt * 32);
#pragma unroll
            for (int nt = 0; nt < 4; ++nt)
                c[nt] = MFMA16(a, ldw(W + O_W1T + (size_t)(16 * nt + r16) * 264 + 128 + kt * 32 + g * 8), c[nt]);
        }
        const int n = 4 * T + g;
        if (n < 25) {
            float v[4] = {s_val[n][0], s_val[n][1], s_val[n][2], s_val[n][3]};
            float e0[4], e1[4], e2[4];
#pragma unroll
            for (int q = 0; q < 4; ++q) {
                e0[q] = s_e[n][q][0]; e1[q] = s_e[n][q][1]; e2[q] = s_e[n][q][2];
            }
#pragma unroll
            for (int nt = 0; nt < 4; ++nt) {
                int col = 16 * nt + r16;
                float we0 = ew1f[256 * 64 + col];
                float we1 = ew1f[257 * 64 + col];
                float we2 = ew1f[258 * 64 + col];
                float base = eb1[col] + bf2f(s_hxi[n * HXS + col]);
                float hs = 0.f;
#pragma unroll
                for (int q = 0; q < 4; ++q) {
                    float pre = c[nt][q] + base
                              + e0[q] * we0 + e1[q] * we1 + e2[q] * we2;
                    hs = fmaf(v[q], fmaxf(pre, 0.f), hs);
                }
                s_hs[n * HSP + col] = f2bf(hs);
            }
        }
    }
    __syncthreads();   // B3

    // ---------------- E2: agg = (hsum @ W2 + cnt*b2) * invd -> bf16 ---------------
    {
        const int mt  = wv & 1;
        const int nth = (wv >> 1) * 4;
        int n_a = 16 * mt + r16; if (n_a > 24) n_a = 24;
        const ushort* A = s_hs + n_a * HSP + g * 8;
        f32x4 c[4] = {{0,0,0,0},{0,0,0,0},{0,0,0,0},{0,0,0,0}};
#pragma unroll
        for (int kt = 0; kt < 2; ++kt) {
            short8 a = ldw(A + kt * 32);
#pragma unroll
            for (int nt = 0; nt < 4; ++nt)
                c[nt] = MFMA16(a, ldw(W + O_W2T + (size_t)((nth + nt) * 16 + r16) * 64 + kt * 32 + g * 8), c[nt]);
        }
#pragma unroll
        for (int nt = 0; nt < 4; ++nt) {
            int col = (nth + nt) * 16 + r16;
            float b2c = eb2[col];
#pragma unroll
            for (int q = 0; q < 4; ++q) {
                int nr = 16 * mt + 4 * g + q;
                if (nr < 25)
                    s_ag[nr * AGP + col] = f2bf(s_invd[nr] * fmaf(s_cnt[nr], b2c, c[nt][q]));
            }
        }
    }
    __syncthreads();   // B4

    // ---------------- N1: g1 = relu([x|agg] @ nW1 + nb1) -> bf16 (aliases hs) -----
    {
        const int mt  = wv & 1;
        const int ntb = (wv >> 1) * 2;
        int n_a = 16 * mt + r16; if (n_a > 24) n_a = 24;
        const ushort* Ax = s_xb + n_a * XBP + g * 8;
        const ushort* Aa = s_ag + n_a * AGP + g * 8;
        f32x4 c[2] = {{0,0,0,0},{0,0,0,0}};
#pragma unroll
        for (int kt = 0; kt < 4; ++kt) {
            short8 a = ldw(Ax + kt * 32);
#pragma unroll
            for (int nt = 0; nt < 2; ++nt)
                c[nt] = MFMA16(a, ldw(W + O_N1T + (size_t)((ntb + nt) * 16 + r16) * 256 + kt * 32 + g * 8), c[nt]);
        }
#pragma unroll
        for (int kt = 0; kt < 4; ++kt) {
            short8 a = ldw(Aa + kt * 32);
#pragma unroll
            for (int nt = 0; nt < 2; ++nt)
                c[nt] = MFMA16(a, ldw(W + O_N1T + (size_t)((ntb + nt) * 16 + r16) * 256 + 128 + kt * 32 + g * 8), c[nt]);
        }
#pragma unroll
        for (int nt = 0; nt < 2; ++nt) {
            int col = (ntb + nt) * 16 + r16;
            float b1c = nb1[col];
#pragma unroll
            for (int q = 0; q < 4; ++q) {
                int nr = 16 * mt + 4 * g + q;
                if (nr < 25)
                    s_g1[nr * HSP + col] = f2bf(fmaxf(c[nt][q] + b1c, 0.f));
            }
        }
    }
    __syncthreads();   // B5   (agg dead from here; y_stb may overwrite it)

    // ---------------- N2: delta GEMM + residual(bf16 x); y->bf16 LDS; LN partials -
    {
        const int mt  = wv & 1;
        const int nth = (wv >> 1) * 4;
        int n_a = 16 * mt + r16; if (n_a > 24) n_a = 24;
        const ushort* A = s_g1 + n_a * HSP + g * 8;
        f32x4 c[4] = {{0,0,0,0},{0,0,0,0},{0,0,0,0},{0,0,0,0}};
#pragma unroll
        for (int kt = 0; kt < 2; ++kt) {
            short8 a = ldw(A + kt * 32);
#pragma unroll
            for (int nt = 0; nt < 4; ++nt)
                c[nt] = MFMA16(a, ldw(W + O_N2T + (size_t)((nth + nt) * 16 + r16) * 64 + kt * 32 + g * 8), c[nt]);
        }
#pragma unroll
        for (int q = 0; q < 4; ++q) {
            int nr = 16 * mt + 4 * g + q;
            int nc = nr < 25 ? nr : 24;
            float hasv = s_has[nc];
            float yv[4];
#pragma unroll
            for (int nt = 0; nt < 4; ++nt) {
                int col = (nth + nt) * 16 + r16;
                float xv = bf2f(s_xb[nc * XBP + col]);
                yv[nt] = fmaf(hasv, c[nt][q] + nb2[col], xv);
            }
            float a = (yv[0] + yv[1]) + (yv[2] + yv[3]);
            float b = fmaf(yv[0], yv[0], fmaf(yv[1], yv[1],
                      fmaf(yv[2], yv[2], yv[3] * yv[3])));
#pragma unroll
            for (int o = 1; o < 16; o <<= 1) {
                a += __shfl_xor(a, o);
                b += __shfl_xor(b, o);
            }
            if (nr < 25) {
#pragma unroll
                for (int nt = 0; nt < 4; ++nt)
                    y_stb[nr * AGP + (nth + nt) * 16 + r16] = f2bf(yv[nt]);
                if (r16 == 0) {
                    s_red[nr][wv >> 1][0] = a;
                    s_red[nr][wv >> 1][1] = b;
                }
            }
        }
    }
    __syncthreads();   // B6

    // ---------------- P7: LN + mask fused into fully-coalesced copy-out -----------
    {
        float* op = out + (size_t)bt * (NN * DD);
        for (int u = t; u < NN * 16; u += 256) {
            int row = u >> 4, q8 = u & 15;      // 8 contiguous cols per step
            uint4 p = *reinterpret_cast<const uint4*>(&y_stb[row * AGP + q8 * 8]);
            float S   = s_red[row][0][0] + s_red[row][1][0];
            float S2  = s_red[row][0][1] + s_red[row][1][1];
            float mu  = S * (1.0f / 128.0f);
            float var = S2 * (1.0f / 128.0f) - mu * mu;
            float rs  = rsqrtf(var + 1e-5f);
            float mk  = s_m[row] ? 1.f : 0.f;
            float2 y01 = up2(p.x), y23 = up2(p.y), y45 = up2(p.z), y67 = up2(p.w);
            const float4 ga = *reinterpret_cast<const float4*>(lng + q8 * 8);
            const float4 gb = *reinterpret_cast<const float4*>(lng + q8 * 8 + 4);
            const float4 ba = *reinterpret_cast<const float4*>(lnb + q8 * 8);
            const float4 bb = *reinterpret_cast<const float4*>(lnb + q8 * 8 + 4);
            float4 o0, o1;
            o0.x = fmaf((y01.x - mu) * rs, ga.x, ba.x) * mk;
            o0.y = fmaf((y01.y - mu) * rs, ga.y, ba.y) * mk;
            o0.z = fmaf((y23.x - mu) * rs, ga.z, ba.z) * mk;
            o0.w = fmaf((y23.y - mu) * rs, ga.w, ba.w) * mk;
            o1.x = fmaf((y45.x - mu) * rs, gb.x, bb.x) * mk;
            o1.y = fmaf((y45.y - mu) * rs, gb.y, bb.y) * mk;
            o1.z = fmaf((y67.x - mu) * rs, gb.z, bb.z) * mk;
            o1.w = fmaf((y67.y - mu) * rs, gb.w, bb.w) * mk;
            *reinterpret_cast<float4*>(op + row * DD + q8 * 8)     = o0;
            *reinterpret_cast<float4*>(op + row * DD + q8 * 8 + 4) = o1;
        }
    }
}

extern "C" void kernel_launch(void* const* d_in, const int* in_sizes, int n_in,
                              void* d_out, int out_size, void* d_ws, size_t ws_size,
                              hipStream_t stream) {
    const float* emb    = (const float*)d_in[0];
    const float* bboxes = (const float*)d_in[1];
    const int*   pmask  = (const int*)  d_in[2];
    const float* ew1    = (const float*)d_in[3];
    const float* eb1    = (const float*)d_in[4];
    const float* ew2    = (const float*)d_in[5];
    const float* eb2    = (const float*)d_in[6];
    const float* nw1    = (const float*)d_in[7];
    const float* nb1    = (const float*)d_in[8];
    const float* nw2    = (const float*)d_in[9];
    const float* nb2    = (const float*)d_in[10];
    const float* lng    = (const float*)d_in[11];
    const float* lnb    = (const float*)d_in[12];
    float* out = (float*)d_out;
    ushort* W  = (ushort*)d_ws;

    prep_kernel<<<64, 256, 0, stream>>>(ew1, ew2, nw1, nw2, W);

    const int BT = in_sizes[2] / NN;   // 2048 frames
    ig7_kernel<<<BT, 256, 0, stream>>>(
        emb, bboxes, pmask, ew1, eb1, eb2, nb1, nb2, lng, lnb, W, out);
}

// Round 8
// 53.370 us; speedup vs baseline: 2.8443x; 1.4965x over previous
//
#include <hip/hip_runtime.h>

#define NN   25
#define DD   128
#define HH   64
#define KK   4
#define RADF 2.5f

#define XBP  136   // ushort stride, [25][128] bf16 rows (272B)
#define HSP  72    // ushort stride, hxi/hs/g1 rows (144B)
#define AGP  136   // ushort stride, agg rows

// ws layout (ushort units) — identical to R4/R7
#define O_W1T 0        // [64][264]   ew1^T  (k<259)
#define O_W2T 16896    // [128][64]   ew2^T
#define O_N1T 25088    // [64][256]   nw1^T
#define O_N2T 41472    // [128][64]   nw2^T

typedef __attribute__((ext_vector_type(8))) short  short8;
typedef __attribute__((ext_vector_type(4))) float  f32x4;

__device__ __forceinline__ ushort f2bf(float x) {
    uint u = __float_as_uint(x);
    u += 0x7fffu + ((u >> 16) & 1u);          // RNE
    return (ushort)(u >> 16);
}
__device__ __forceinline__ float bf2f(ushort u) {
    return __uint_as_float((uint)u << 16);
}
__device__ __forceinline__ uint pack2(float a, float b) {
    return (uint)f2bf(a) | ((uint)f2bf(b) << 16);
}
__device__ __forceinline__ short8 ldw(const ushort* p) {
    return *reinterpret_cast<const short8*>(p);
}
#define MFMA16(a, b, c) __builtin_amdgcn_mfma_f32_16x16x32_bf16((a), (b), (c), 0, 0, 0)

__global__ void prep_kernel(const float* __restrict__ ew1, const float* __restrict__ ew2,
                            const float* __restrict__ nw1, const float* __restrict__ nw2,
                            ushort* __restrict__ w) {
    int tid = blockIdx.x * blockDim.x + threadIdx.x;
    int stride = gridDim.x * blockDim.x;
    for (int e = tid; e < 259 * 64; e += stride) {
        int k = e >> 6, c = e & 63;
        w[O_W1T + c * 264 + k] = f2bf(ew1[e]);
    }
    for (int e = tid; e < 64 * 128; e += stride) {
        int k = e >> 7, d = e & 127;
        w[O_W2T + d * 64 + k] = f2bf(ew2[e]);
    }
    for (int e = tid; e < 256 * 64; e += stride) {
        int k = e >> 6, c = e & 63;
        w[O_N1T + c * 256 + k] = f2bf(nw1[e]);
    }
    for (int e = tid; e < 64 * 128; e += stride) {
        int k = e >> 7, d = e & 127;
        w[O_N2T + d * 64 + k] = f2bf(nw2[e]);
    }
}

__global__ __launch_bounds__(64, 2) void ig8_kernel(
    const float* __restrict__ emb,      // [BT,25,128]
    const float* __restrict__ bboxes,   // [BT,25,4]
    const int*   __restrict__ pmask,    // [BT,25]
    const float* __restrict__ ew1f,     // [259,64] f32 (e-rows 256..258)
    const float* __restrict__ eb1,
    const float* __restrict__ eb2,
    const float* __restrict__ nb1,
    const float* __restrict__ nb2,
    const float* __restrict__ lng,
    const float* __restrict__ lnb,
    const ushort* __restrict__ W,       // prepped bf16 transposed weights
    float* __restrict__ out)
{
    const int bt  = blockIdx.x;          // one frame per 64-thread block (one wave)
    const int ln  = threadIdx.x;         // 0..63
    const int g   = ln >> 4;             // k-chunk / C-row group (0..3)
    const int r16 = ln & 15;

    __shared__ ushort s_xb[NN * XBP];            // 6800 B  bf16 x
    __shared__ __align__(16) char s_R[7200];     // hxi|hs, later ag overlay
    __shared__ ushort s_g1v[NN * HSP];           // 3600 B  g1
    __shared__ float  s_ev[NN][KK][4];           // 1600 B  e0,e1,e2,val
    __shared__ short  s_idxs[NN][KK];            // 200 B
    __shared__ float  s_meta[NN][4];             // 400 B   cnt,invd,has,mask
    // total ~19.8 KB -> 8 blocks/CU (all 8 frames per CU co-resident)

    ushort* s_hxi = reinterpret_cast<ushort*>(s_R);          // [25][72]
    ushort* s_hs  = reinterpret_cast<ushort*>(s_R + 3600);   // [25][72]
    ushort* s_ag  = reinterpret_cast<ushort*>(s_R);          // [25][136], after E1b

    // ---------------- P0: stage x (bf16) ----------------
    {
        const float4* src4 = reinterpret_cast<const float4*>(emb + (size_t)bt * (NN * DD));
        for (int u = ln; u < NN * 16; u += 64) {
            int row = u >> 4, q = u & 15;
            float4 f0 = src4[row * 32 + q * 2];
            float4 f1 = src4[row * 32 + q * 2 + 1];
            uint4 p;
            p.x = pack2(f0.x, f0.y); p.y = pack2(f0.z, f0.w);
            p.z = pack2(f1.x, f1.y); p.w = pack2(f1.z, f1.w);
            *reinterpret_cast<uint4*>(&s_xb[row * XBP + q * 8]) = p;
        }
    }

    // ---------------- P1: geometry + KNN (shuffle-based, all lanes) ---------------
    {
        const int n = (ln < NN) ? ln : NN - 1;
        const float4 b4 = *reinterpret_cast<const float4*>(bboxes + ((size_t)bt * NN + n) * 4);
        const float cxn = b4.x, cyn = b4.y;
        const float hvn = fmaxf(b4.w, 1e-6f);
        const int   mn  = pmask[(size_t)bt * NN + n];
        const float inv = 1.0f / hvn;
        float best[KK] = {1e30f, 1e30f, 1e30f, 1e30f};
        int   bidx[KK] = {0, 0, 0, 0};
        for (int j = 0; j < NN; ++j) {
            float cxj = __shfl(cxn, j);
            float cyj = __shfl(cyn, j);
            int   mj  = __shfl(mn, j);
            float dx = cxn - cxj, dy = cyn - cyj;
            float dn = sqrtf(fmaf(dx, dx, fmaf(dy, dy, 1e-6f))) * inv;
            bool  pv = (mn != 0) && (mj != 0) && (j != n);
            float cv = pv ? dn : 1e6f;
            int   ci = j;
#pragma unroll
            for (int kk = 0; kk < KK; ++kk) {       // stable insertion, lowest idx on tie
                if (cv < best[kk]) {
                    float tv = best[kk]; best[kk] = cv; cv = tv;
                    int   ti = bidx[kk]; bidx[kk] = ci; ci = ti;
                }
            }
        }
        float cnt = 0.f;
        float e0v[KK], e1v[KK], e2v[KK], vvv[KK];
#pragma unroll
        for (int k = 0; k < KK; ++k) {
            int bj = bidx[k];
            float cxb = __shfl(cxn, bj);
            float cyb = __shfl(cyn, bj);
            float val = (best[k] < RADF) ? 1.f : 0.f;
            cnt += val;
            float dx = cxn - cxb, dy = cyn - cyb;
            e0v[k] = dx * inv;
            e1v[k] = dy * inv;
            e2v[k] = sqrtf(fmaf(dx, dx, fmaf(dy, dy, 1e-6f))) * inv;
            vvv[k] = val;
        }
        if (ln < NN) {
#pragma unroll
            for (int k = 0; k < KK; ++k) {
                s_ev[n][k][0] = e0v[k];
                s_ev[n][k][1] = e1v[k];
                s_ev[n][k][2] = e2v[k];
                s_ev[n][k][3] = vvv[k];
                s_idxs[n][k]  = (short)bidx[k];
            }
            s_meta[n][0] = cnt;
            s_meta[n][1] = 1.0f / fmaxf(cnt, 1.0f);
            s_meta[n][2] = (cnt > 0.f) ? 1.f : 0.f;
            s_meta[n][3] = mn ? 1.f : 0.f;
        }
    }
    __syncthreads();   // single-wave: waitcnt drain only, no inter-wave wait

    // ---------------- E1a: hxi[25][64] = x @ W1[0:128] ----------------------------
#pragma unroll
    for (int mt = 0; mt < 2; ++mt) {
        int na = 16 * mt + r16; if (na > 24) na = 24;
        const ushort* A = s_xb + na * XBP + g * 8;
        short8 a0 = ldw(A), a1 = ldw(A + 32), a2 = ldw(A + 64), a3 = ldw(A + 96);
        f32x4 c[4] = {{0,0,0,0},{0,0,0,0},{0,0,0,0},{0,0,0,0}};
#pragma unroll
        for (int nt = 0; nt < 4; ++nt) {
            const ushort* Wp = W + O_W1T + (size_t)(16 * nt + r16) * 264 + g * 8;
            c[nt] = MFMA16(a0, ldw(Wp),      c[nt]);
            c[nt] = MFMA16(a1, ldw(Wp + 32), c[nt]);
            c[nt] = MFMA16(a2, ldw(Wp + 64), c[nt]);
            c[nt] = MFMA16(a3, ldw(Wp + 96), c[nt]);
        }
#pragma unroll
        for (int q = 0; q < 4; ++q) {
            int nr = 16 * mt + 4 * g + q;
            if (nr < 25) {
#pragma unroll
                for (int nt = 0; nt < 4; ++nt)
                    s_hxi[nr * HSP + 16 * nt + r16] = f2bf(c[nt][q]);
            }
        }
    }
    __syncthreads();

    // ---------------- E1b: xj GEMM + fused relu/val-k-sum -> hsum -----------------
    for (int T = 0; T < 7; ++T) {
        int r = 16 * T + r16; if (r > 99) r = 99;
        const int jn = s_idxs[r >> 2][r & 3];
        const ushort* A = s_xb + jn * XBP + g * 8;
        short8 a0 = ldw(A), a1 = ldw(A + 32), a2 = ldw(A + 64), a3 = ldw(A + 96);
        f32x4 c[4] = {{0,0,0,0},{0,0,0,0},{0,0,0,0},{0,0,0,0}};
#pragma unroll
        for (int nt = 0; nt < 4; ++nt) {
            const ushort* Wp = W + O_W1T + (size_t)(16 * nt + r16) * 264 + 128 + g * 8;
            c[nt] = MFMA16(a0, ldw(Wp),      c[nt]);
            c[nt] = MFMA16(a1, ldw(Wp + 32), c[nt]);
            c[nt] = MFMA16(a2, ldw(Wp + 64), c[nt]);
            c[nt] = MFMA16(a3, ldw(Wp + 96), c[nt]);
        }
        const int n = 4 * T + g;
        if (n < 25) {
            float v0 = s_ev[n][0][3], v1 = s_ev[n][1][3];
            float v2 = s_ev[n][2][3], v3 = s_ev[n][3][3];
            float e0q[4], e1q[4], e2q[4];
#pragma unroll
            for (int q = 0; q < 4; ++q) {
                e0q[q] = s_ev[n][q][0]; e1q[q] = s_ev[n][q][1]; e2q[q] = s_ev[n][q][2];
            }
#pragma unroll
            for (int nt = 0; nt < 4; ++nt) {
                int col = 16 * nt + r16;
                float we0 = ew1f[256 * 64 + col];
                float we1 = ew1f[257 * 64 + col];
                float we2 = ew1f[258 * 64 + col];
                float base = eb1[col] + bf2f(s_hxi[n * HSP + col]);
                float p0 = c[nt][0] + base + e0q[0] * we0 + e1q[0] * we1 + e2q[0] * we2;
                float p1 = c[nt][1] + base + e0q[1] * we0 + e1q[1] * we1 + e2q[1] * we2;
                float p2 = c[nt][2] + base + e0q[2] * we0 + e1q[2] * we1 + e2q[2] * we2;
                float p3 = c[nt][3] + base + e0q[3] * we0 + e1q[3] * we1 + e2q[3] * we2;
                float hs = fmaf(v0, fmaxf(p0, 0.f),
                           fmaf(v1, fmaxf(p1, 0.f),
                           fmaf(v2, fmaxf(p2, 0.f),
                                v3 * fmaxf(p3, 0.f))));
                s_hs[n * HSP + col] = f2bf(hs);
            }
        }
    }
    __syncthreads();

    // ---------------- E2: agg = (hsum @ W2 + cnt*b2) * invd  (ag overlays R) ------
    {
        short8 hA00, hA01, hA10, hA11;     // prefetch ALL hs A-frags before ag writes
        {
            int na0 = r16;               // rows 0..15
            int na1 = 16 + r16; if (na1 > 24) na1 = 24;
            hA00 = ldw(s_hs + na0 * HSP + g * 8);
            hA01 = ldw(s_hs + na0 * HSP + 32 + g * 8);
            hA10 = ldw(s_hs + na1 * HSP + g * 8);
            hA11 = ldw(s_hs + na1 * HSP + 32 + g * 8);
        }
#pragma unroll
        for (int mt = 0; mt < 2; ++mt) {
            short8 A0 = mt ? hA10 : hA00;
            short8 A1 = mt ? hA11 : hA01;
#pragma unroll
            for (int nh = 0; nh < 2; ++nh) {
                f32x4 c[4] = {{0,0,0,0},{0,0,0,0},{0,0,0,0},{0,0,0,0}};
#pragma unroll
                for (int nt = 0; nt < 4; ++nt) {
                    const ushort* Wp = W + O_W2T + (size_t)((nh * 4 + nt) * 16 + r16) * 64 + g * 8;
                    c[nt] = MFMA16(A0, ldw(Wp),      c[nt]);
                    c[nt] = MFMA16(A1, ldw(Wp + 32), c[nt]);
                }
#pragma unroll
                for (int nt = 0; nt < 4; ++nt) {
                    int col = (nh * 4 + nt) * 16 + r16;
                    float b2c = eb2[col];
#pragma unroll
                    for (int q = 0; q < 4; ++q) {
                        int nr = 16 * mt + 4 * g + q;
                        if (nr < 25) {
                            float agv = s_meta[nr][1] * fmaf(s_meta[nr][0], b2c, c[nt][q]);
                            s_ag[nr * AGP + col] = f2bf(agv);
                        }
                    }
                }
            }
        }
    }
    __syncthreads();

    // ---------------- N1: g1 = relu([x|agg] @ nW1 + nb1) --------------------------
#pragma unroll
    for (int mt = 0; mt < 2; ++mt) {
        int na = 16 * mt + r16; if (na > 24) na = 24;
        const ushort* Ax = s_xb + na * XBP + g * 8;
        const ushort* Aa = s_ag + na * AGP + g * 8;
        short8 ax0 = ldw(Ax), ax1 = ldw(Ax + 32), ax2 = ldw(Ax + 64), ax3 = ldw(Ax + 96);
        short8 aa0 = ldw(Aa), aa1 = ldw(Aa + 32), aa2 = ldw(Aa + 64), aa3 = ldw(Aa + 96);
#pragma unroll
        for (int nh = 0; nh < 2; ++nh) {
            f32x4 c[2] = {{0,0,0,0},{0,0,0,0}};
#pragma unroll
            for (int nt = 0; nt < 2; ++nt) {
                const ushort* Wp = W + O_N1T + (size_t)((nh * 2 + nt) * 16 + r16) * 256 + g * 8;
                c[nt] = MFMA16(ax0, ldw(Wp),       c[nt]);
                c[nt] = MFMA16(ax1, ldw(Wp +  32), c[nt]);
                c[nt] = MFMA16(ax2, ldw(Wp +  64), c[nt]);
                c[nt] = MFMA16(ax3, ldw(Wp +  96), c[nt]);
                c[nt] = MFMA16(aa0, ldw(Wp + 128), c[nt]);
                c[nt] = MFMA16(aa1, ldw(Wp + 160), c[nt]);
                c[nt] = MFMA16(aa2, ldw(Wp + 192), c[nt]);
                c[nt] = MFMA16(aa3, ldw(Wp + 224), c[nt]);
            }
#pragma unroll
            for (int nt = 0; nt < 2; ++nt) {
                int col = (nh * 2 + nt) * 16 + r16;
                float b1c = nb1[col];
#pragma unroll
                for (int q = 0; q < 4; ++q) {
                    int nr = 16 * mt + 4 * g + q;
                    if (nr < 25)
                        s_g1v[nr * HSP + col] = f2bf(fmaxf(c[nt][q] + b1c, 0.f));
                }
            }
        }
    }
    __syncthreads();

    // ---------------- N2: delta GEMM + residual + LN + mask + store ---------------
#pragma unroll
    for (int mt = 0; mt < 2; ++mt) {
        int na = 16 * mt + r16; if (na > 24) na = 24;
        short8 aG0 = ldw(s_g1v + na * HSP + g * 8);
        short8 aG1 = ldw(s_g1v + na * HSP + 32 + g * 8);
        float y[2][4][4];
#pragma unroll
        for (int nh = 0; nh < 2; ++nh) {
            f32x4 c[4] = {{0,0,0,0},{0,0,0,0},{0,0,0,0},{0,0,0,0}};
#pragma unroll
            for (int nt = 0; nt < 4; ++nt) {
                const ushort* Wp = W + O_N2T + (size_t)((nh * 4 + nt) * 16 + r16) * 64 + g * 8;
                c[nt] = MFMA16(aG0, ldw(Wp),      c[nt]);
                c[nt] = MFMA16(aG1, ldw(Wp + 32), c[nt]);
            }
#pragma unroll
            for (int q = 0; q < 4; ++q) {
                int nr = 16 * mt + 4 * g + q;
                int nc = nr < 25 ? nr : 24;
                float has = s_meta[nc][2];
#pragma unroll
                for (int nt = 0; nt < 4; ++nt) {
                    int col = (nh * 4 + nt) * 16 + r16;
                    y[nh][nt][q] = fmaf(has, c[nt][q] + nb2[col], bf2f(s_xb[nc * XBP + col]));
                }
            }
        }
#pragma unroll
        for (int q = 0; q < 4; ++q) {
            int nr = 16 * mt + 4 * g + q;
            int nc = nr < 25 ? nr : 24;
            float a = 0.f, b = 0.f;
#pragma unroll
            for (int nh = 0; nh < 2; ++nh)
#pragma unroll
                for (int nt = 0; nt < 4; ++nt) {
                    float yv = y[nh][nt][q];
                    a += yv;
                    b = fmaf(yv, yv, b);
                }
#pragma unroll
            for (int o = 1; o < 16; o <<= 1) {
                a += __shfl_xor(a, o);
                b += __shfl_xor(b, o);
            }
            float mu  = a * (1.0f / 128.0f);
            float var = b * (1.0f / 128.0f) - mu * mu;
            float rs  = rsqrtf(var + 1e-5f);
            float mk  = s_meta[nc][3];
            if (nr < 25) {
                float* op = out + (size_t)bt * (NN * DD) + nr * DD;
#pragma unroll
                for (int nh = 0; nh < 2; ++nh)
#pragma unroll
                    for (int nt = 0; nt < 4; ++nt) {
                        int col = (nh * 4 + nt) * 16 + r16;
                        op[col] = fmaf((y[nh][nt][q] - mu) * rs, lng[col], lnb[col]) * mk;
                    }
            }
        }
    }
}

extern "C" void kernel_launch(void* const* d_in, const int* in_sizes, int n_in,
                              void* d_out, int out_size, void* d_ws, size_t ws_size,
                              hipStream_t stream) {
    const float* emb    = (const float*)d_in[0];
    const float* bboxes = (const float*)d_in[1];
    const int*   pmask  = (const int*)  d_in[2];
    const float* ew1    = (const float*)d_in[3];
    const float* eb1    = (const float*)d_in[4];
    const float* ew2    = (const float*)d_in[5];
    const float* eb2    = (const float*)d_in[6];
    const float* nw1    = (const float*)d_in[7];
    const float* nb1    = (const float*)d_in[8];
    const float* nw2    = (const float*)d_in[9];
    const float* nb2    = (const float*)d_in[10];
    const float* lng    = (const float*)d_in[11];
    const float* lnb    = (const float*)d_in[12];
    float* out = (float*)d_out;
    ushort* W  = (ushort*)d_ws;

    prep_kernel<<<64, 256, 0, stream>>>(ew1, ew2, nw1, nw2, W);

    const int BT = in_sizes[2] / NN;   // 2048 frames
    ig8_kernel<<<BT, 64, 0, stream>>>(
        emb, bboxes, pmask, ew1, eb1, eb2, nb1, nb2, lng, lnb, W, out);
}

// Round 9
// 48.534 us; speedup vs baseline: 3.1277x; 1.0996x over previous
//
#include <hip/hip_runtime.h>

#define NN   25
#define DD   128
#define HH   64
#define KK   4
#define RADF 2.5f

#define XBP  136   // ushort stride, [25][128] bf16 rows (272B)
#define HSP  72    // ushort stride, hxi/hs/g1 rows (144B)
#define AGP  136   // ushort stride, agg rows

// ws layout (ushort units) — identical to R4/R7/R8
#define O_W1T 0        // [64][264]   ew1^T  (k<259)
#define O_W2T 16896    // [128][64]   ew2^T
#define O_N1T 25088    // [64][256]   nw1^T
#define O_N2T 41472    // [128][64]   nw2^T

typedef __attribute__((ext_vector_type(8))) short  short8;
typedef __attribute__((ext_vector_type(4))) float  f32x4;

__device__ __forceinline__ ushort f2bf(float x) {
    uint u = __float_as_uint(x);
    u += 0x7fffu + ((u >> 16) & 1u);          // RNE
    return (ushort)(u >> 16);
}
__device__ __forceinline__ float bf2f(ushort u) {
    return __uint_as_float((uint)u << 16);
}
__device__ __forceinline__ uint pack2(float a, float b) {
    return (uint)f2bf(a) | ((uint)f2bf(b) << 16);
}
__device__ __forceinline__ short8 ldw(const ushort* p) {
    return *reinterpret_cast<const short8*>(p);
}
#define MFMA16(a, b, c) __builtin_amdgcn_mfma_f32_16x16x32_bf16((a), (b), (c), 0, 0, 0)

__global__ void prep_kernel(const float* __restrict__ ew1, const float* __restrict__ ew2,
                            const float* __restrict__ nw1, const float* __restrict__ nw2,
                            ushort* __restrict__ w) {
    int tid = blockIdx.x * blockDim.x + threadIdx.x;
    int stride = gridDim.x * blockDim.x;
    for (int e = tid; e < 259 * 64; e += stride) {
        int k = e >> 6, c = e & 63;
        w[O_W1T + c * 264 + k] = f2bf(ew1[e]);
    }
    for (int e = tid; e < 64 * 128; e += stride) {
        int k = e >> 7, d = e & 127;
        w[O_W2T + d * 64 + k] = f2bf(ew2[e]);
    }
    for (int e = tid; e < 256 * 64; e += stride) {
        int k = e >> 6, c = e & 63;
        w[O_N1T + c * 256 + k] = f2bf(nw1[e]);
    }
    for (int e = tid; e < 64 * 128; e += stride) {
        int k = e >> 7, d = e & 127;
        w[O_N2T + d * 64 + k] = f2bf(nw2[e]);
    }
}

__global__ __launch_bounds__(64, 2) void ig9_kernel(
    const float* __restrict__ emb,      // [BT,25,128]
    const float* __restrict__ bboxes,   // [BT,25,4]
    const int*   __restrict__ pmask,    // [BT,25]
    const float* __restrict__ ew1f,     // [259,64] f32 (e-rows 256..258)
    const float* __restrict__ eb1,
    const float* __restrict__ eb2,
    const float* __restrict__ nb1,
    const float* __restrict__ nb2,
    const float* __restrict__ lng,
    const float* __restrict__ lnb,
    const ushort* __restrict__ W,       // prepped bf16 transposed weights
    float* __restrict__ out)
{
    const int bt  = blockIdx.x;          // one frame per 64-thread block (one wave)
    const int ln  = threadIdx.x;         // 0..63
    const int g   = ln >> 4;             // k-chunk / C-row group (0..3)
    const int r16 = ln & 15;

    __shared__ ushort s_xb[NN * XBP];            // 6800 B  bf16 x
    __shared__ __align__(16) char s_R[7200];     // hxi|hs, later ag overlay
    __shared__ ushort s_g1v[NN * HSP];           // 3600 B  g1
    __shared__ float  s_ev[NN][KK][4];           // 1600 B  e0,e1,e2,val
    __shared__ short  s_idxs[NN][KK];            // 200 B
    __shared__ float  s_meta[NN][4];             // 400 B   cnt,invd,has,mask
    // ~19.8 KB -> 8 blocks/CU

    ushort* s_hxi = reinterpret_cast<ushort*>(s_R);          // [25][72]
    ushort* s_hs  = reinterpret_cast<ushort*>(s_R + 3600);   // [25][72]
    ushort* s_ag  = reinterpret_cast<ushort*>(s_R);          // [25][136], after E1b

    // ---------------- P0: stage x (bf16) ----------------
    {
        const float4* src4 = reinterpret_cast<const float4*>(emb + (size_t)bt * (NN * DD));
        for (int u = ln; u < NN * 16; u += 64) {
            int row = u >> 4, q = u & 15;
            float4 f0 = src4[row * 32 + q * 2];
            float4 f1 = src4[row * 32 + q * 2 + 1];
            uint4 p;
            p.x = pack2(f0.x, f0.y); p.y = pack2(f0.z, f0.w);
            p.z = pack2(f1.x, f1.y); p.w = pack2(f1.z, f1.w);
            *reinterpret_cast<uint4*>(&s_xb[row * XBP + q * 8]) = p;
        }
    }

    // ---------------- P1: geometry + KNN (shuffle-based) ----------------
    {
        const int n = (ln < NN) ? ln : NN - 1;
        const float4 b4 = *reinterpret_cast<const float4*>(bboxes + ((size_t)bt * NN + n) * 4);
        const float cxn = b4.x, cyn = b4.y;
        const float hvn = fmaxf(b4.w, 1e-6f);
        const int   mn  = pmask[(size_t)bt * NN + n];
        const float inv = 1.0f / hvn;
        float best[KK] = {1e30f, 1e30f, 1e30f, 1e30f};
        int   bidx[KK] = {0, 0, 0, 0};
        for (int j = 0; j < NN; ++j) {
            float cxj = __shfl(cxn, j);
            float cyj = __shfl(cyn, j);
            int   mj  = __shfl(mn, j);
            float dx = cxn - cxj, dy = cyn - cyj;
            float dn = sqrtf(fmaf(dx, dx, fmaf(dy, dy, 1e-6f))) * inv;
            bool  pv = (mn != 0) && (mj != 0) && (j != n);
            float cv = pv ? dn : 1e6f;
            int   ci = j;
#pragma unroll
            for (int kk = 0; kk < KK; ++kk) {       // stable insertion, lowest idx on tie
                if (cv < best[kk]) {
                    float tv = best[kk]; best[kk] = cv; cv = tv;
                    int   ti = bidx[kk]; bidx[kk] = ci; ci = ti;
                }
            }
        }
        float cnt = 0.f;
        float e0v[KK], e1v[KK], e2v[KK], vvv[KK];
#pragma unroll
        for (int k = 0; k < KK; ++k) {
            int bj = bidx[k];
            float cxb = __shfl(cxn, bj);
            float cyb = __shfl(cyn, bj);
            float val = (best[k] < RADF) ? 1.f : 0.f;
            cnt += val;
            float dx = cxn - cxb, dy = cyn - cyb;
            e0v[k] = dx * inv;
            e1v[k] = dy * inv;
            e2v[k] = sqrtf(fmaf(dx, dx, fmaf(dy, dy, 1e-6f))) * inv;
            vvv[k] = val;
        }
        if (ln < NN) {
#pragma unroll
            for (int k = 0; k < KK; ++k) {
                s_ev[n][k][0] = e0v[k];
                s_ev[n][k][1] = e1v[k];
                s_ev[n][k][2] = e2v[k];
                s_ev[n][k][3] = vvv[k];
                s_idxs[n][k]  = (short)bidx[k];
            }
            s_meta[n][0] = cnt;
            s_meta[n][1] = 1.0f / fmaxf(cnt, 1.0f);
            s_meta[n][2] = (cnt > 0.f) ? 1.f : 0.f;
            s_meta[n][3] = mn ? 1.f : 0.f;
        }
    }
    __syncthreads();

    // ---------------- E1a: hxi = x @ W1[0:128]  (1 weight pass, 2 M-tiles) --------
    {
        int na1 = 16 + r16; if (na1 > 24) na1 = 24;
        const ushort* A0 = s_xb + r16 * XBP + g * 8;
        const ushort* A1 = s_xb + na1 * XBP + g * 8;
        f32x4 c[2][4] = {};
#pragma unroll
        for (int kt = 0; kt < 4; ++kt) {
            short8 b[4];
#pragma unroll
            for (int nt = 0; nt < 4; ++nt)
                b[nt] = ldw(W + O_W1T + (size_t)(16 * nt + r16) * 264 + kt * 32 + g * 8);
            short8 a0 = ldw(A0 + kt * 32);
            short8 a1 = ldw(A1 + kt * 32);
#pragma unroll
            for (int nt = 0; nt < 4; ++nt) {
                c[0][nt] = MFMA16(a0, b[nt], c[0][nt]);
                c[1][nt] = MFMA16(a1, b[nt], c[1][nt]);
            }
        }
#pragma unroll
        for (int mt = 0; mt < 2; ++mt)
#pragma unroll
            for (int q = 0; q < 4; ++q) {
                int nr = 16 * mt + 4 * g + q;
                if (nr < 25) {
#pragma unroll
                    for (int nt = 0; nt < 4; ++nt)
                        s_hxi[nr * HSP + 16 * nt + r16] = f2bf(c[mt][nt][q]);
                }
            }
    }
    __syncthreads();

    // ---------------- E1b: xj GEMM, 1 weight pass over 7 M-tiles ------------------
    {
        int jn[7];
#pragma unroll
        for (int T = 0; T < 7; ++T) {
            int r = 16 * T + r16; if (r > 99) r = 99;
            jn[T] = s_idxs[r >> 2][r & 3];
        }
        f32x4 c[7][4] = {};
#pragma unroll
        for (int kt = 0; kt < 4; ++kt) {
            short8 b[4];
#pragma unroll
            for (int nt = 0; nt < 4; ++nt)
                b[nt] = ldw(W + O_W1T + (size_t)(16 * nt + r16) * 264 + 128 + kt * 32 + g * 8);
#pragma unroll
            for (int T = 0; T < 7; ++T) {
                short8 a = ldw(s_xb + jn[T] * XBP + kt * 32 + g * 8);
#pragma unroll
                for (int nt = 0; nt < 4; ++nt)
                    c[T][nt] = MFMA16(a, b[nt], c[T][nt]);
            }
        }
        // epilogue: hoisted per-col constants, then per-T relu/val-sum
        float we0[4], we1[4], we2[4], bb1[4];
#pragma unroll
        for (int nt = 0; nt < 4; ++nt) {
            int col = 16 * nt + r16;
            we0[nt] = ew1f[256 * 64 + col];
            we1[nt] = ew1f[257 * 64 + col];
            we2[nt] = ew1f[258 * 64 + col];
            bb1[nt] = eb1[col];
        }
#pragma unroll
        for (int T = 0; T < 7; ++T) {
            const int n = 4 * T + g;
            if (n < 25) {
                float v0 = s_ev[n][0][3], v1 = s_ev[n][1][3];
                float v2 = s_ev[n][2][3], v3 = s_ev[n][3][3];
                float e0q[4], e1q[4], e2q[4];
#pragma unroll
                for (int q = 0; q < 4; ++q) {
                    e0q[q] = s_ev[n][q][0]; e1q[q] = s_ev[n][q][1]; e2q[q] = s_ev[n][q][2];
                }
#pragma unroll
                for (int nt = 0; nt < 4; ++nt) {
                    int col = 16 * nt + r16;
                    float base = bb1[nt] + bf2f(s_hxi[n * HSP + col]);
                    float p0 = c[T][nt][0] + base + e0q[0] * we0[nt] + e1q[0] * we1[nt] + e2q[0] * we2[nt];
                    float p1 = c[T][nt][1] + base + e0q[1] * we0[nt] + e1q[1] * we1[nt] + e2q[1] * we2[nt];
                    float p2 = c[T][nt][2] + base + e0q[2] * we0[nt] + e1q[2] * we1[nt] + e2q[2] * we2[nt];
                    float p3 = c[T][nt][3] + base + e0q[3] * we0[nt] + e1q[3] * we1[nt] + e2q[3] * we2[nt];
                    float hs = fmaf(v0, fmaxf(p0, 0.f),
                               fmaf(v1, fmaxf(p1, 0.f),
                               fmaf(v2, fmaxf(p2, 0.f),
                                    v3 * fmaxf(p3, 0.f))));
                    s_hs[n * HSP + col] = f2bf(hs);
                }
            }
        }
    }
    __syncthreads();

    // ---------------- E2: agg = (hs @ W2 + cnt*b2)*invd  (1 pass, ag overlays R) --
    {
        int na1 = 16 + r16; if (na1 > 24) na1 = 24;
        const ushort* A0 = s_hs + r16 * HSP + g * 8;
        const ushort* A1 = s_hs + na1 * HSP + g * 8;
        f32x4 c[2][8] = {};
#pragma unroll
        for (int kt = 0; kt < 2; ++kt) {
            short8 a0 = ldw(A0 + kt * 32);
            short8 a1 = ldw(A1 + kt * 32);
#pragma unroll
            for (int nt = 0; nt < 8; ++nt) {
                short8 b = ldw(W + O_W2T + (size_t)(16 * nt + r16) * 64 + kt * 32 + g * 8);
                c[0][nt] = MFMA16(a0, b, c[0][nt]);
                c[1][nt] = MFMA16(a1, b, c[1][nt]);
            }
        }
        __syncthreads();   // hs reads fully drained before ag overlays the region
#pragma unroll
        for (int nt = 0; nt < 8; ++nt) {
            int col = 16 * nt + r16;
            float b2c = eb2[col];
#pragma unroll
            for (int mt = 0; mt < 2; ++mt)
#pragma unroll
                for (int q = 0; q < 4; ++q) {
                    int nr = 16 * mt + 4 * g + q;
                    if (nr < 25) {
                        float agv = s_meta[nr][1] * fmaf(s_meta[nr][0], b2c, c[mt][nt][q]);
                        s_ag[nr * AGP + col] = f2bf(agv);
                    }
                }
        }
    }
    __syncthreads();

    // ---------------- N1: g1 = relu([x|ag] @ nW1 + nb1)  (1 weight pass) ----------
    {
        int na1 = 16 + r16; if (na1 > 24) na1 = 24;
        const ushort* Ax0 = s_xb + r16 * XBP + g * 8;
        const ushort* Ax1 = s_xb + na1 * XBP + g * 8;
        const ushort* Aa0 = s_ag + r16 * AGP + g * 8;
        const ushort* Aa1 = s_ag + na1 * AGP + g * 8;
        f32x4 c[2][4] = {};
#pragma unroll
        for (int kt = 0; kt < 8; ++kt) {
            const ushort* Ap0 = (kt < 4) ? (Ax0 + kt * 32) : (Aa0 + (kt - 4) * 32);
            const ushort* Ap1 = (kt < 4) ? (Ax1 + kt * 32) : (Aa1 + (kt - 4) * 32);
            short8 a0 = ldw(Ap0);
            short8 a1 = ldw(Ap1);
#pragma unroll
            for (int nt = 0; nt < 4; ++nt) {
                short8 b = ldw(W + O_N1T + (size_t)(16 * nt + r16) * 256 + kt * 32 + g * 8);
                c[0][nt] = MFMA16(a0, b, c[0][nt]);
                c[1][nt] = MFMA16(a1, b, c[1][nt]);
            }
        }
#pragma unroll
        for (int nt = 0; nt < 4; ++nt) {
            int col = 16 * nt + r16;
            float b1c = nb1[col];
#pragma unroll
            for (int mt = 0; mt < 2; ++mt)
#pragma unroll
                for (int q = 0; q < 4; ++q) {
                    int nr = 16 * mt + 4 * g + q;
                    if (nr < 25)
                        s_g1v[nr * HSP + col] = f2bf(fmaxf(c[mt][nt][q] + b1c, 0.f));
                }
        }
    }
    __syncthreads();

    // ---------------- N2: delta GEMM (1 pass) + residual + LN + mask + store ------
    {
        int na1 = 16 + r16; if (na1 > 24) na1 = 24;
        const ushort* A0 = s_g1v + r16 * HSP + g * 8;
        const ushort* A1 = s_g1v + na1 * HSP + g * 8;
        f32x4 c[2][8] = {};
#pragma unroll
        for (int kt = 0; kt < 2; ++kt) {
            short8 a0 = ldw(A0 + kt * 32);
            short8 a1 = ldw(A1 + kt * 32);
#pragma unroll
            for (int nt = 0; nt < 8; ++nt) {
                short8 b = ldw(W + O_N2T + (size_t)(16 * nt + r16) * 64 + kt * 32 + g * 8);
                c[0][nt] = MFMA16(a0, b, c[0][nt]);
                c[1][nt] = MFMA16(a1, b, c[1][nt]);
            }
        }
        float nb2c[8], glc[8], blc[8];
#pragma unroll
        for (int nt = 0; nt < 8; ++nt) {
            int col = 16 * nt + r16;
            nb2c[nt] = nb2[col];
            glc[nt]  = lng[col];
            blc[nt]  = lnb[col];
        }
#pragma unroll
        for (int mt = 0; mt < 2; ++mt) {
#pragma unroll
            for (int q = 0; q < 4; ++q) {
                int nr = 16 * mt + 4 * g + q;
                int nc = nr < 25 ? nr : 24;
                float has = s_meta[nc][2];
                float y[8];
                float a = 0.f, b = 0.f;
#pragma unroll
                for (int nt = 0; nt < 8; ++nt) {
                    int col = 16 * nt + r16;
                    float yv = fmaf(has, c[mt][nt][q] + nb2c[nt], bf2f(s_xb[nc * XBP + col]));
                    y[nt] = yv;
                    a += yv;
                    b = fmaf(yv, yv, b);
                }
#pragma unroll
                for (int o = 1; o < 16; o <<= 1) {
                    a += __shfl_xor(a, o);
                    b += __shfl_xor(b, o);
                }
                float mu  = a * (1.0f / 128.0f);
                float var = b * (1.0f / 128.0f) - mu * mu;
                float rs  = rsqrtf(var + 1e-5f);
                float mk  = s_meta[nc][3];
                if (nr < 25) {
                    float* op = out + (size_t)bt * (NN * DD) + nr * DD;
#pragma unroll
                    for (int nt = 0; nt < 8; ++nt) {
                        int col = 16 * nt + r16;
                        op[col] = fmaf((y[nt] - mu) * rs, glc[nt], blc[nt]) * mk;
                    }
                }
            }
        }
    }
}

extern "C" void kernel_launch(void* const* d_in, const int* in_sizes, int n_in,
                              void* d_out, int out_size, void* d_ws, size_t ws_size,
                              hipStream_t stream) {
    const float* emb    = (const float*)d_in[0];
    const float* bboxes = (const float*)d_in[1];
    const int*   pmask  = (const int*)  d_in[2];
    const float* ew1    = (const float*)d_in[3];
    const float* eb1    = (const float*)d_in[4];
    const float* ew2    = (const float*)d_in[5];
    const float* eb2    = (const float*)d_in[6];
    const float* nw1    = (const float*)d_in[7];
    const float* nb1    = (const float*)d_in[8];
    const float* nw2    = (const float*)d_in[9];
    const float* nb2    = (const float*)d_in[10];
    const float* lng    = (const float*)d_in[11];
    const float* lnb    = (const float*)d_in[12];
    float* out = (float*)d_out;
    ushort* W  = (ushort*)d_ws;

    prep_kernel<<<64, 256, 0, stream>>>(ew1, ew2, nw1, nw2, W);

    const int BT = in_sizes[2] / NN;   // 2048 frames
    ig9_kernel<<<BT, 64, 0, stream>>>(
        emb, bboxes, pmask, ew1, eb1, eb2, nb1, nb2, lng, lnb, W, out);
}

// Round 10
// 42.628 us; speedup vs baseline: 3.5610x; 1.1386x over previous
//
#include <hip/hip_runtime.h>

#define NN   25
#define DD   128
#define HH   64
#define KK   4
#define RADF 2.5f

#define XBP  136   // ushort stride, [25][128] bf16 rows (272B)
#define HSP  72    // ushort stride, hxi/hs/g1 rows (144B)
#define AGP  136   // ushort stride, agg rows

// ws layout (ushort units) — identical to R4..R9
#define O_W1T 0        // [64][264]   ew1^T  (k<259)
#define O_W2T 16896    // [128][64]   ew2^T
#define O_N1T 25088    // [64][256]   nw1^T
#define O_N2T 41472    // [128][64]   nw2^T

typedef __attribute__((ext_vector_type(8))) short  short8;
typedef __attribute__((ext_vector_type(4))) float  f32x4;

__device__ __forceinline__ ushort f2bf(float x) {
    uint u = __float_as_uint(x);
    u += 0x7fffu + ((u >> 16) & 1u);          // RNE
    return (ushort)(u >> 16);
}
__device__ __forceinline__ float bf2f(ushort u) {
    return __uint_as_float((uint)u << 16);
}
__device__ __forceinline__ uint pack2(float a, float b) {
    return (uint)f2bf(a) | ((uint)f2bf(b) << 16);
}
__device__ __forceinline__ short8 ldw(const ushort* p) {
    return *reinterpret_cast<const short8*>(p);
}
#define MFMA16(a, b, c) __builtin_amdgcn_mfma_f32_16x16x32_bf16((a), (b), (c), 0, 0, 0)

__global__ void prep_kernel(const float* __restrict__ ew1, const float* __restrict__ ew2,
                            const float* __restrict__ nw1, const float* __restrict__ nw2,
                            ushort* __restrict__ w) {
    int tid = blockIdx.x * blockDim.x + threadIdx.x;
    int stride = gridDim.x * blockDim.x;
    for (int e = tid; e < 259 * 64; e += stride) {
        int k = e >> 6, c = e & 63;
        w[O_W1T + c * 264 + k] = f2bf(ew1[e]);
    }
    for (int e = tid; e < 64 * 128; e += stride) {
        int k = e >> 7, d = e & 127;
        w[O_W2T + d * 64 + k] = f2bf(ew2[e]);
    }
    for (int e = tid; e < 256 * 64; e += stride) {
        int k = e >> 6, c = e & 63;
        w[O_N1T + c * 256 + k] = f2bf(nw1[e]);
    }
    for (int e = tid; e < 64 * 128; e += stride) {
        int k = e >> 7, d = e & 127;
        w[O_N2T + d * 64 + k] = f2bf(nw2[e]);
    }
}

__global__ __launch_bounds__(128, 4) void ig10_kernel(
    const float* __restrict__ emb,      // [BT,25,128]
    const float* __restrict__ bboxes,   // [BT,25,4]
    const int*   __restrict__ pmask,    // [BT,25]
    const float* __restrict__ ew1f,     // [259,64] f32 (e-rows 256..258)
    const float* __restrict__ eb1,
    const float* __restrict__ eb2,
    const float* __restrict__ nb1,
    const float* __restrict__ nb2,
    const float* __restrict__ lng,
    const float* __restrict__ lnb,
    const ushort* __restrict__ W,       // prepped bf16 transposed weights
    float* __restrict__ out)
{
    const int bt  = blockIdx.x;          // one frame per 128-thread block (2 waves)
    const int t   = threadIdx.x;
    const int wv  = t >> 6;              // wave 0 / 1: N-column half
    const int ln  = t & 63;
    const int g   = ln >> 4;             // k-chunk / C-row group (0..3)
    const int r16 = ln & 15;
    const int cb  = 2 * wv;              // nt base for 64-col phases
    const int cb4 = 4 * wv;              // nt base for 128-col phases

    __shared__ ushort s_xb[NN * XBP];            // 6800 B  bf16 x
    __shared__ __align__(16) char s_R[7200];     // hxi|hs, later ag overlay
    __shared__ ushort s_g1v[NN * HSP];           // 3600 B  g1
    __shared__ __align__(16) char s_misc[1600];  // s_ev, later s_red overlay
    __shared__ short  s_idxs[NN][KK];            // 200 B
    __shared__ float  s_meta[NN][4];             // 400 B  cnt,invd,has,mask
    // ~19.8 KB -> 8 blocks/CU -> 16 waves/CU

    float (*s_ev)[KK][4] = reinterpret_cast<float(*)[KK][4]>(s_misc);  // E1b-dead
    float (*s_red)[2][2] = reinterpret_cast<float(*)[2][2]>(s_misc);   // N2 overlay
    ushort* s_hxi = reinterpret_cast<ushort*>(s_R);          // [25][72]
    ushort* s_hs  = reinterpret_cast<ushort*>(s_R + 3600);   // [25][72]
    ushort* s_ag  = reinterpret_cast<ushort*>(s_R);          // [25][136], after E1b

    if (wv == 0) {
        // ---------------- P0: stage x (bf16), wave 0 ----------------
        const float4* src4 = reinterpret_cast<const float4*>(emb + (size_t)bt * (NN * DD));
        for (int u = ln; u < NN * 16; u += 64) {
            int row = u >> 4, q = u & 15;
            float4 f0 = src4[row * 32 + q * 2];
            float4 f1 = src4[row * 32 + q * 2 + 1];
            uint4 p;
            p.x = pack2(f0.x, f0.y); p.y = pack2(f0.z, f0.w);
            p.z = pack2(f1.x, f1.y); p.w = pack2(f1.z, f1.w);
            *reinterpret_cast<uint4*>(&s_xb[row * XBP + q * 8]) = p;
        }
    } else {
        // ---------------- P1: geometry + KNN (shuffle-based), wave 1 --------------
        const int n = (ln < NN) ? ln : NN - 1;
        const float4 b4 = *reinterpret_cast<const float4*>(bboxes + ((size_t)bt * NN + n) * 4);
        const float cxn = b4.x, cyn = b4.y;
        const float hvn = fmaxf(b4.w, 1e-6f);
        const int   mn  = pmask[(size_t)bt * NN + n];
        const float inv = 1.0f / hvn;
        float best[KK] = {1e30f, 1e30f, 1e30f, 1e30f};
        int   bidx[KK] = {0, 0, 0, 0};
        for (int j = 0; j < NN; ++j) {
            float cxj = __shfl(cxn, j);
            float cyj = __shfl(cyn, j);
            int   mj  = __shfl(mn, j);
            float dx = cxn - cxj, dy = cyn - cyj;
            float dn = sqrtf(fmaf(dx, dx, fmaf(dy, dy, 1e-6f))) * inv;
            bool  pv = (mn != 0) && (mj != 0) && (j != n);
            float cv = pv ? dn : 1e6f;
            int   ci = j;
#pragma unroll
            for (int kk = 0; kk < KK; ++kk) {       // stable insertion, lowest idx on tie
                if (cv < best[kk]) {
                    float tv = best[kk]; best[kk] = cv; cv = tv;
                    int   ti = bidx[kk]; bidx[kk] = ci; ci = ti;
                }
            }
        }
        float cnt = 0.f;
        float e0v[KK], e1v[KK], e2v[KK], vvv[KK];
#pragma unroll
        for (int k = 0; k < KK; ++k) {
            int bj = bidx[k];
            float cxb = __shfl(cxn, bj);
            float cyb = __shfl(cyn, bj);
            float val = (best[k] < RADF) ? 1.f : 0.f;
            cnt += val;
            float dx = cxn - cxb, dy = cyn - cyb;
            e0v[k] = dx * inv;
            e1v[k] = dy * inv;
            e2v[k] = sqrtf(fmaf(dx, dx, fmaf(dy, dy, 1e-6f))) * inv;
            vvv[k] = val;
        }
        if (ln < NN) {
#pragma unroll
            for (int k = 0; k < KK; ++k) {
                s_ev[n][k][0] = e0v[k];
                s_ev[n][k][1] = e1v[k];
                s_ev[n][k][2] = e2v[k];
                s_ev[n][k][3] = vvv[k];
                s_idxs[n][k]  = (short)bidx[k];
            }
            s_meta[n][0] = cnt;
            s_meta[n][1] = 1.0f / fmaxf(cnt, 1.0f);
            s_meta[n][2] = (cnt > 0.f) ? 1.f : 0.f;
            s_meta[n][3] = mn ? 1.f : 0.f;
        }
    }
    __syncthreads();

    // ---------------- E1a: hxi = x @ W1[0:128]  (wave = 2 col-tiles) --------------
    {
        int na1 = 16 + r16; if (na1 > 24) na1 = 24;
        const ushort* A0 = s_xb + r16 * XBP + g * 8;
        const ushort* A1 = s_xb + na1 * XBP + g * 8;
        f32x4 c[2][2] = {};
#pragma unroll
        for (int kt = 0; kt < 4; ++kt) {
            short8 b0 = ldw(W + O_W1T + (size_t)(16 * (cb + 0) + r16) * 264 + kt * 32 + g * 8);
            short8 b1 = ldw(W + O_W1T + (size_t)(16 * (cb + 1) + r16) * 264 + kt * 32 + g * 8);
            short8 a0 = ldw(A0 + kt * 32);
            short8 a1 = ldw(A1 + kt * 32);
            c[0][0] = MFMA16(a0, b0, c[0][0]); c[0][1] = MFMA16(a0, b1, c[0][1]);
            c[1][0] = MFMA16(a1, b0, c[1][0]); c[1][1] = MFMA16(a1, b1, c[1][1]);
        }
#pragma unroll
        for (int mt = 0; mt < 2; ++mt)
#pragma unroll
            for (int q = 0; q < 4; ++q) {
                int nr = 16 * mt + 4 * g + q;
                if (nr < 25) {
#pragma unroll
                    for (int ntl = 0; ntl < 2; ++ntl)
                        s_hxi[nr * HSP + 16 * (cb + ntl) + r16] = f2bf(c[mt][ntl][q]);
                }
            }
    }
    // no barrier: hxi cols are wave-local (written and read by the same wave)

    // ---------------- E1b: xj GEMM, 1 weight pass over 7 M-tiles ------------------
    {
        int jn[7];
#pragma unroll
        for (int T = 0; T < 7; ++T) {
            int r = 16 * T + r16; if (r > 99) r = 99;
            jn[T] = s_idxs[r >> 2][r & 3];
        }
        f32x4 c[7][2] = {};
#pragma unroll
        for (int kt = 0; kt < 4; ++kt) {
            short8 b0 = ldw(W + O_W1T + (size_t)(16 * (cb + 0) + r16) * 264 + 128 + kt * 32 + g * 8);
            short8 b1 = ldw(W + O_W1T + (size_t)(16 * (cb + 1) + r16) * 264 + 128 + kt * 32 + g * 8);
#pragma unroll
            for (int T = 0; T < 7; ++T) {
                short8 a = ldw(s_xb + jn[T] * XBP + kt * 32 + g * 8);
                c[T][0] = MFMA16(a, b0, c[T][0]);
                c[T][1] = MFMA16(a, b1, c[T][1]);
            }
        }
        float we0[2], we1[2], we2[2], bb1[2];
#pragma unroll
        for (int ntl = 0; ntl < 2; ++ntl) {
            int col = 16 * (cb + ntl) + r16;
            we0[ntl] = ew1f[256 * 64 + col];
            we1[ntl] = ew1f[257 * 64 + col];
            we2[ntl] = ew1f[258 * 64 + col];
            bb1[ntl] = eb1[col];
        }
#pragma unroll
        for (int T = 0; T < 7; ++T) {
            const int n = 4 * T + g;
            if (n < 25) {
                float v0 = s_ev[n][0][3], v1 = s_ev[n][1][3];
                float v2 = s_ev[n][2][3], v3 = s_ev[n][3][3];
                float e0q[4], e1q[4], e2q[4];
#pragma unroll
                for (int q = 0; q < 4; ++q) {
                    e0q[q] = s_ev[n][q][0]; e1q[q] = s_ev[n][q][1]; e2q[q] = s_ev[n][q][2];
                }
#pragma unroll
                for (int ntl = 0; ntl < 2; ++ntl) {
                    int col = 16 * (cb + ntl) + r16;
                    float base = bb1[ntl] + bf2f(s_hxi[n * HSP + col]);
                    float p0 = c[T][ntl][0] + base + e0q[0] * we0[ntl] + e1q[0] * we1[ntl] + e2q[0] * we2[ntl];
                    float p1 = c[T][ntl][1] + base + e0q[1] * we0[ntl] + e1q[1] * we1[ntl] + e2q[1] * we2[ntl];
                    float p2 = c[T][ntl][2] + base + e0q[2] * we0[ntl] + e1q[2] * we1[ntl] + e2q[2] * we2[ntl];
                    float p3 = c[T][ntl][3] + base + e0q[3] * we0[ntl] + e1q[3] * we1[ntl] + e2q[3] * we2[ntl];
                    float hs = fmaf(v0, fmaxf(p0, 0.f),
                               fmaf(v1, fmaxf(p1, 0.f),
                               fmaf(v2, fmaxf(p2, 0.f),
                                    v3 * fmaxf(p3, 0.f))));
                    s_hs[n * HSP + col] = f2bf(hs);
                }
            }
        }
    }
    __syncthreads();   // hs: full 64 cols needed by E2 (cross-wave)

    // ---------------- E2: agg = (hs @ W2 + cnt*b2)*invd  (wave = 4 col-tiles) -----
    {
        int na1 = 16 + r16; if (na1 > 24) na1 = 24;
        const ushort* A0 = s_hs + r16 * HSP + g * 8;
        const ushort* A1 = s_hs + na1 * HSP + g * 8;
        f32x4 c[2][4] = {};
#pragma unroll
        for (int kt = 0; kt < 2; ++kt) {
            short8 a0 = ldw(A0 + kt * 32);
            short8 a1 = ldw(A1 + kt * 32);
#pragma unroll
            for (int ntl = 0; ntl < 4; ++ntl) {
                short8 b = ldw(W + O_W2T + (size_t)(16 * (cb4 + ntl) + r16) * 64 + kt * 32 + g * 8);
                c[0][ntl] = MFMA16(a0, b, c[0][ntl]);
                c[1][ntl] = MFMA16(a1, b, c[1][ntl]);
            }
        }
        __syncthreads();   // all hs reads drained before ag overlays the region
#pragma unroll
        for (int ntl = 0; ntl < 4; ++ntl) {
            int col = 16 * (cb4 + ntl) + r16;
            float b2c = eb2[col];
#pragma unroll
            for (int mt = 0; mt < 2; ++mt)
#pragma unroll
                for (int q = 0; q < 4; ++q) {
                    int nr = 16 * mt + 4 * g + q;
                    if (nr < 25) {
                        float agv = s_meta[nr][1] * fmaf(s_meta[nr][0], b2c, c[mt][ntl][q]);
                        s_ag[nr * AGP + col] = f2bf(agv);
                    }
                }
        }
    }
    __syncthreads();   // ag: full 128 cols needed by N1

    // ---------------- N1: g1 = relu([x|ag] @ nW1 + nb1)  (wave = 2 col-tiles) -----
    {
        int na1 = 16 + r16; if (na1 > 24) na1 = 24;
        const ushort* Ax0 = s_xb + r16 * XBP + g * 8;
        const ushort* Ax1 = s_xb + na1 * XBP + g * 8;
        const ushort* Aa0 = s_ag + r16 * AGP + g * 8;
        const ushort* Aa1 = s_ag + na1 * AGP + g * 8;
        f32x4 c[2][2] = {};
#pragma unroll
        for (int kt = 0; kt < 8; ++kt) {
            const ushort* Ap0 = (kt < 4) ? (Ax0 + kt * 32) : (Aa0 + (kt - 4) * 32);
            const ushort* Ap1 = (kt < 4) ? (Ax1 + kt * 32) : (Aa1 + (kt - 4) * 32);
            short8 a0 = ldw(Ap0);
            short8 a1 = ldw(Ap1);
#pragma unroll
            for (int ntl = 0; ntl < 2; ++ntl) {
                short8 b = ldw(W + O_N1T + (size_t)(16 * (cb + ntl) + r16) * 256 + kt * 32 + g * 8);
                c[0][ntl] = MFMA16(a0, b, c[0][ntl]);
                c[1][ntl] = MFMA16(a1, b, c[1][ntl]);
            }
        }
#pragma unroll
        for (int ntl = 0; ntl < 2; ++ntl) {
            int col = 16 * (cb + ntl) + r16;
            float b1c = nb1[col];
#pragma unroll
            for (int mt = 0; mt < 2; ++mt)
#pragma unroll
                for (int q = 0; q < 4; ++q) {
                    int nr = 16 * mt + 4 * g + q;
                    if (nr < 25)
                        s_g1v[nr * HSP + col] = f2bf(fmaxf(c[mt][ntl][q] + b1c, 0.f));
                }
        }
    }
    __syncthreads();   // g1: full 64 cols needed by N2

    // ---------------- N2: delta GEMM + residual + LN partials + store -------------
    {
        int na1 = 16 + r16; if (na1 > 24) na1 = 24;
        const ushort* A0 = s_g1v + r16 * HSP + g * 8;
        const ushort* A1 = s_g1v + na1 * HSP + g * 8;
        f32x4 c[2][4] = {};
#pragma unroll
        for (int kt = 0; kt < 2; ++kt) {
            short8 a0 = ldw(A0 + kt * 32);
            short8 a1 = ldw(A1 + kt * 32);
#pragma unroll
            for (int ntl = 0; ntl < 4; ++ntl) {
                short8 b = ldw(W + O_N2T + (size_t)(16 * (cb4 + ntl) + r16) * 64 + kt * 32 + g * 8);
                c[0][ntl] = MFMA16(a0, b, c[0][ntl]);
                c[1][ntl] = MFMA16(a1, b, c[1][ntl]);
            }
        }
        float nb2c[4], glc[4], blc[4];
#pragma unroll
        for (int ntl = 0; ntl < 4; ++ntl) {
            int col = 16 * (cb4 + ntl) + r16;
            nb2c[ntl] = nb2[col];
            glc[ntl]  = lng[col];
            blc[ntl]  = lnb[col];
        }
        float y[2][4][4];
#pragma unroll
        for (int mt = 0; mt < 2; ++mt) {
#pragma unroll
            for (int q = 0; q < 4; ++q) {
                int nr = 16 * mt + 4 * g + q;
                int nc = nr < 25 ? nr : 24;
                float has = s_meta[nc][2];
                float a = 0.f, b = 0.f;
#pragma unroll
                for (int ntl = 0; ntl < 4; ++ntl) {
                    int col = 16 * (cb4 + ntl) + r16;
                    float yv = fmaf(has, c[mt][ntl][q] + nb2c[ntl], bf2f(s_xb[nc * XBP + col]));
                    y[mt][ntl][q] = yv;
                    a += yv;
                    b = fmaf(yv, yv, b);
                }
#pragma unroll
                for (int o = 1; o < 16; o <<= 1) {
                    a += __shfl_xor(a, o);
                    b += __shfl_xor(b, o);
                }
                if (r16 == 0 && nr < 25) {
                    s_red[nr][wv][0] = a;
                    s_red[nr][wv][1] = b;
                }
            }
        }
        __syncthreads();   // both waves' LN partials in place
#pragma unroll
        for (int mt = 0; mt < 2; ++mt) {
#pragma unroll
            for (int q = 0; q < 4; ++q) {
                int nr = 16 * mt + 4 * g + q;
                int nc = nr < 25 ? nr : 24;
                float S   = s_red[nc][0][0] + s_red[nc][1][0];
                float S2  = s_red[nc][0][1] + s_red[nc][1][1];
                float mu  = S * (1.0f / 128.0f);
                float var = S2 * (1.0f / 128.0f) - mu * mu;
                float rs  = rsqrtf(var + 1e-5f);
                float mk  = s_meta[nc][3];
                if (nr < 25) {
                    float* op = out + (size_t)bt * (NN * DD) + nr * DD;
#pragma unroll
                    for (int ntl = 0; ntl < 4; ++ntl) {
                        int col = 16 * (cb4 + ntl) + r16;
                        op[col] = fmaf((y[mt][ntl][q] - mu) * rs, glc[ntl], blc[ntl]) * mk;
                    }
                }
            }
        }
    }
}

extern "C" void kernel_launch(void* const* d_in, const int* in_sizes, int n_in,
                              void* d_out, int out_size, void* d_ws, size_t ws_size,
                              hipStream_t stream) {
    const float* emb    = (const float*)d_in[0];
    const float* bboxes = (const float*)d_in[1];
    const int*   pmask  = (const int*)  d_in[2];
    const float* ew1    = (const float*)d_in[3];
    const float* eb1    = (const float*)d_in[4];
    const float* ew2    = (const float*)d_in[5];
    const float* eb2    = (const float*)d_in[6];
    const float* nw1    = (const float*)d_in[7];
    const float* nb1    = (const float*)d_in[8];
    const float* nw2    = (const float*)d_in[9];
    const float* nb2    = (const float*)d_in[10];
    const float* lng    = (const float*)d_in[11];
    const float* lnb    = (const float*)d_in[12];
    float* out = (float*)d_out;
    ushort* W  = (ushort*)d_ws;

    prep_kernel<<<64, 256, 0, stream>>>(ew1, ew2, nw1, nw2, W);

    const int BT = in_sizes[2] / NN;   // 2048 frames
    ig10_kernel<<<BT, 128, 0, stream>>>(
        emb, bboxes, pmask, ew1, eb1, eb2, nb1, nb2, lng, lnb, W, out);
}